// Round 6
// baseline (185.223 us; speedup 1.0000x reference)
//
#include <hip/hip_runtime.h>

// ---------------------------------------------------------------------------
// RoPE Multi-Headed Attention (quirky softmax(exp(qr·kr)/den) variant)
// B=2, S=2048, D=1024, H=16, HD=64
// ---------------------------------------------------------------------------

#define Bn 2
#define Sn 2048
#define Dn 1024
#define Hn 16
#define HDn 64

typedef __attribute__((ext_vector_type(8))) short bf16x8;
typedef __attribute__((ext_vector_type(8))) unsigned short u16x8;
typedef __attribute__((ext_vector_type(4))) unsigned short u16x4;
typedef __attribute__((ext_vector_type(4))) float f32x4;

#define MFMA(a, b, c) __builtin_amdgcn_mfma_f32_16x16x32_bf16(a, b, c, 0, 0, 0)
#define Z4 ((f32x4){0.f, 0.f, 0.f, 0.f})

// 0.125 * log2(e): folds the 1/sqrt(HD) scale and the exp->exp2 change into Q
#define PRESC 0.18033688011112042f
// log2(log2(e)): A = a*log2(e) = 2^(s' - L2 + C2)
#define C2 0.5287663729448977f

#define EXP2(x) __builtin_amdgcn_exp2f(x)
#define LOG2(x) __builtin_amdgcn_logf(x)

__device__ __forceinline__ unsigned short f2bf(float f) {
  unsigned int u = __builtin_bit_cast(unsigned int, f);
  u = (u + 0x7fffu + ((u >> 16) & 1u)) >> 16;
  return (unsigned short)u;
}

__device__ __forceinline__ unsigned int cvtpk(float lo, float hi) {
  unsigned int r;
  asm("v_cvt_pk_bf16_f32 %0, %1, %2" : "=v"(r) : "v"(lo), "v"(hi));
  return r;
}

// async global->LDS, 16B per lane; dst is wave-uniform base (lane writes +lane*16B)
__device__ __forceinline__ void gll16(const unsigned short* g, unsigned short* l) {
  __builtin_amdgcn_global_load_lds((const __attribute__((address_space(1))) void*)g,
                                   (__attribute__((address_space(3))) void*)l, 16, 0, 0);
}

// swizzled fragment read: LDS slot c of row r holds source chunk c^(r&7)
#define FR(T, row, x) (*(const bf16x8*)&(T)[(row) * 64 + (((x) ^ ((row) & 7)) * 8)])

// ---------------------------------------------------------------------------
// 0. k_pre: merged trig table + weight transpose + activation convert.
//    blocks [0,256): trig; [256,1280): wtrans; [1280,7424): cvt
// ---------------------------------------------------------------------------
__global__ __launch_bounds__(256) void k_pre(
    const float* __restrict__ W0, const float* __restrict__ W1,
    const float* __restrict__ W2, const float* __restrict__ W3,
    unsigned short* __restrict__ O0, unsigned short* __restrict__ O1,
    unsigned short* __restrict__ O2, unsigned short* __restrict__ O3,
    const float* __restrict__ qa, const float* __restrict__ ka, const float* __restrict__ va,
    unsigned short* __restrict__ oq, unsigned short* __restrict__ ok,
    unsigned short* __restrict__ ov, float2* __restrict__ T) {
  __shared__ float t[64][65];
  const int b = blockIdx.x;
  const int tid = threadIdx.x;
  if (b < 256) {
    const int idx = b * 256 + tid;  // 65536
    const int s = idx >> 5, i = idx & 31;
    const float theta = powf(1000.f, -(float)i / 32.f);
    const float pm = (float)s * theta;
    T[idx] = make_float2(cosf(pm), sinf(pm));
  } else if (b < 1280) {
    const int w = b - 256;
    const int which = w >> 8, rem = w & 255;
    const float* W = (which == 0) ? W0 : (which == 1) ? W1 : (which == 2) ? W2 : W3;
    unsigned short* O = (which == 0) ? O0 : (which == 1) ? O1 : (which == 2) ? O2 : O3;
    const int kb = (rem >> 4) * 64, nb = (rem & 15) * 64;
#pragma unroll
    for (int rep = 0; rep < 16; ++rep) {
      const int e = rep * 256 + tid;
      const int k = e >> 6, n = e & 63;
      t[k][n] = W[(kb + k) * Dn + nb + n];
    }
    __syncthreads();
#pragma unroll
    for (int rep = 0; rep < 16; ++rep) {
      const int e = rep * 256 + tid;
      const int n = e >> 6, k = e & 63;
      O[(nb + n) * Dn + kb + k] = f2bf(t[k][n]);
    }
  } else {
    const int c = b - 1280;  // 6144 blocks
    const int z = c >> 11, cx = c & 2047;
    const float* s = (z == 0) ? qa : (z == 1) ? ka : va;
    unsigned short* d = (z == 0) ? oq : (z == 1) ? ok : ov;
    const size_t idx = ((size_t)cx * 256 + tid) * 8;
    float4 a0 = *(const float4*)(s + idx);
    float4 b0 = *(const float4*)(s + idx + 4);
    u16x8 pk;
    pk[0] = f2bf(a0.x); pk[1] = f2bf(a0.y); pk[2] = f2bf(a0.z); pk[3] = f2bf(a0.w);
    pk[4] = f2bf(b0.x); pk[5] = f2bf(b0.y); pk[6] = f2bf(b0.z); pk[7] = f2bf(b0.w);
    *(u16x8*)(d + idx) = pk;
  }
}

// ---------------------------------------------------------------------------
// 1. Fused QKV projection GEMM (gll-staged). grid (32, 8, 3); z = {Q,K,V}.
//    Q: prescaled by PRESC; Q/K write base + roped; V writes Vt [b,h,hd,s].
// ---------------------------------------------------------------------------
__global__ __launch_bounds__(256) void k_gemm_proj(
    const unsigned short* __restrict__ Qa, const unsigned short* __restrict__ Ka,
    const unsigned short* __restrict__ Va,
    const unsigned short* __restrict__ Wq, const unsigned short* __restrict__ Wk,
    const unsigned short* __restrict__ Wv,
    const float* __restrict__ bqp, const float* __restrict__ bkp, const float* __restrict__ bvp,
    const float2* __restrict__ trig,
    unsigned short* __restrict__ Qb, unsigned short* __restrict__ Kb,
    unsigned short* __restrict__ Qr, unsigned short* __restrict__ Kr,
    unsigned short* __restrict__ Vt) {
  __shared__ unsigned short Al[128 * 64];
  __shared__ unsigned short Bl[128 * 64];
  const int tid = threadIdx.x;
  const int wave = tid >> 6, lane = tid & 63, g = lane >> 4, li = lane & 15;
  const int mbase = blockIdx.x * 128, nbase = blockIdx.y * 128;
  const int wm = wave >> 1, wn = wave & 1;
  const int which = blockIdx.z;
  const unsigned short* A = (which == 0) ? Qa : (which == 1) ? Ka : Va;
  const unsigned short* Wt = (which == 0) ? Wq : (which == 1) ? Wk : Wv;
  const float* bias = (which == 0) ? bqp : (which == 1) ? bkp : bvp;

  f32x4 acc[4][4];
#pragma unroll
  for (int i = 0; i < 4; ++i)
#pragma unroll
    for (int j = 0; j < 4; ++j) acc[i][j] = Z4;

  float bv4[4];
#pragma unroll
  for (int nt = 0; nt < 4; ++nt) bv4[nt] = bias[nbase + wn * 64 + nt * 16 + li];

  const int lr8 = lane >> 3, lc = lane & 7;
  const int xc8 = (lc ^ lr8) * 8;
  const unsigned short* srcA = A + (size_t)(mbase + wave * 32 + lr8) * Dn + xc8;
  const unsigned short* srcB = Wt + (size_t)(nbase + wave * 32 + lr8) * Dn + xc8;

  for (int kb = 0; kb < Dn; kb += 64) {
    __syncthreads();
#pragma unroll
    for (int i = 0; i < 4; ++i) {
      gll16(srcA + kb + (size_t)i * (8 * Dn), &Al[(wave * 32 + i * 8) * 64]);
      gll16(srcB + kb + (size_t)i * (8 * Dn), &Bl[(wave * 32 + i * 8) * 64]);
    }
    __syncthreads();
#pragma unroll
    for (int kc = 0; kc < 2; ++kc) {
      bf16x8 af[4], bfr[4];
#pragma unroll
      for (int mt = 0; mt < 4; ++mt) af[mt] = FR(Al, wm * 64 + mt * 16 + li, kc * 4 + g);
#pragma unroll
      for (int nt = 0; nt < 4; ++nt) bfr[nt] = FR(Bl, wn * 64 + nt * 16 + li, kc * 4 + g);
#pragma unroll
      for (int mt = 0; mt < 4; ++mt)
#pragma unroll
        for (int nt = 0; nt < 4; ++nt)
          acc[mt][nt] = MFMA(af[mt], bfr[nt], acc[mt][nt]);
    }
  }

  if (which < 2) {
    unsigned short* Ob = (which == 0) ? Qb : Kb;
    unsigned short* Or = (which == 0) ? Qr : Kr;
    const float presc = (which == 0) ? PRESC : 1.f;
#pragma unroll
    for (int mt = 0; mt < 4; ++mt) {
#pragma unroll
      for (int nt = 0; nt < 4; ++nt) {
        const int n = nbase + wn * 64 + nt * 16 + li;
        const int h = n >> 6, hd = n & 63;
        const int ti = hd >> 1;
        const float sgn = (hd & 1) ? 1.f : -1.f;
#pragma unroll
        for (int r = 0; r < 4; ++r) {
          const int m = mbase + wm * 64 + mt * 16 + 4 * g + r;
          const int b = m >> 11, s = m & (Sn - 1);
          const float v = (acc[mt][nt][r] + bv4[nt]) * presc;
          const size_t oi = (((size_t)(b * Hn + h)) * Sn + s) * HDn + hd;
          Ob[oi] = f2bf(v);
          const float p = __shfl_xor(v, 1);
          const float2 cs = trig[(s << 5) + ti];
          Or[oi] = f2bf(fmaf(sgn * p, cs.y, v * cs.x));
        }
      }
    }
  } else {
#pragma unroll
    for (int mt = 0; mt < 4; ++mt) {
#pragma unroll
      for (int nt = 0; nt < 4; ++nt) {
        const int n = nbase + wn * 64 + nt * 16 + li;
        const int h = n >> 6, hd = n & 63;
        const int m0 = mbase + wm * 64 + mt * 16 + 4 * g;
        const int b = m0 >> 11, s0 = m0 & (Sn - 1);
        u16x4 pk;
#pragma unroll
        for (int r = 0; r < 4; ++r) pk[r] = f2bf(acc[mt][nt][r] + bv4[nt]);
        *(u16x4*)&Vt[(((size_t)(b * Hn + h)) * HDn + hd) * Sn + s0] = pk;
      }
    }
  }
}

// ---------------------------------------------------------------------------
// 2. Output GEMM 64x128 tile (gll-staged): A bf16 [4096][1024], out f32 + bias
// ---------------------------------------------------------------------------
__global__ __launch_bounds__(256) void k_gemm_out(const unsigned short* __restrict__ A,
                                                  const unsigned short* __restrict__ Wt,
                                                  const float* __restrict__ bias,
                                                  float* __restrict__ out) {
  __shared__ unsigned short Al[64 * 64];
  __shared__ unsigned short Bl[128 * 64];
  const int tid = threadIdx.x;
  const int wave = tid >> 6, lane = tid & 63, g = lane >> 4, li = lane & 15;
  const int mbase = blockIdx.x * 64, nbase = blockIdx.y * 128;
  const int wm = wave >> 1, wn = wave & 1;

  f32x4 acc[2][4];
#pragma unroll
  for (int i = 0; i < 2; ++i)
#pragma unroll
    for (int j = 0; j < 4; ++j) acc[i][j] = Z4;

  float bv4[4];
#pragma unroll
  for (int nt = 0; nt < 4; ++nt) bv4[nt] = bias[nbase + wn * 64 + nt * 16 + li];

  const int lr8 = lane >> 3, lc = lane & 7;
  const int xc8 = (lc ^ lr8) * 8;
  const unsigned short* srcA = A + (size_t)(mbase + wave * 16 + lr8) * Dn + xc8;
  const unsigned short* srcB = Wt + (size_t)(nbase + wave * 32 + lr8) * Dn + xc8;

  for (int kb = 0; kb < Dn; kb += 64) {
    __syncthreads();
#pragma unroll
    for (int i = 0; i < 2; ++i)
      gll16(srcA + kb + (size_t)i * (8 * Dn), &Al[(wave * 16 + i * 8) * 64]);
#pragma unroll
    for (int i = 0; i < 4; ++i)
      gll16(srcB + kb + (size_t)i * (8 * Dn), &Bl[(wave * 32 + i * 8) * 64]);
    __syncthreads();
#pragma unroll
    for (int kc = 0; kc < 2; ++kc) {
      bf16x8 af[2], bfr[4];
#pragma unroll
      for (int mt = 0; mt < 2; ++mt) af[mt] = FR(Al, wm * 32 + mt * 16 + li, kc * 4 + g);
#pragma unroll
      for (int nt = 0; nt < 4; ++nt) bfr[nt] = FR(Bl, wn * 64 + nt * 16 + li, kc * 4 + g);
#pragma unroll
      for (int mt = 0; mt < 2; ++mt)
#pragma unroll
        for (int nt = 0; nt < 4; ++nt)
          acc[mt][nt] = MFMA(af[mt], bfr[nt], acc[mt][nt]);
    }
  }

#pragma unroll
  for (int mt = 0; mt < 2; ++mt)
#pragma unroll
    for (int nt = 0; nt < 4; ++nt) {
      const int n = nbase + wn * 64 + nt * 16 + li;
#pragma unroll
      for (int r = 0; r < 4; ++r) {
        const int m = mbase + wm * 32 + mt * 16 + 4 * g + r;
        out[(size_t)m * Dn + n] = acc[mt][nt][r] + bv4[nt];
      }
    }
}

// ---------------------------------------------------------------------------
// 3. k_den (pass A): den over ALL k, G=4 q-groups per wave (64 q/wave).
//    Block = 2 waves = 128 q-rows. grid 512 (XCD-remapped). Writes Lc to Lbuf.
// ---------------------------------------------------------------------------
__global__ __launch_bounds__(128, 4) void k_den(const unsigned short* __restrict__ Qb,
                                                const unsigned short* __restrict__ Kb,
                                                float* __restrict__ Lbuf) {
  __shared__ unsigned short KT[2][128 * 64];  // 32 KB double-buffered Kb tile

  const int tid = threadIdx.x;
  const int wave = tid >> 6, lane = tid & 63, g = lane >> 4, li = lane & 15;
  const int raw = blockIdx.x;  // 512 blocks; remap for per-XCD bh locality
  const int xcd = raw & 7, idx = raw >> 3;
  const int bh = xcd * 4 + (idx >> 4);
  const int qb = idx & 15;
  const int q0 = qb * 128 + wave * 64;
  const size_t kvbase = (size_t)bh * (Sn * HDn);

  bf16x8 qbf[4][2];
#pragma unroll
  for (int j = 0; j < 4; ++j)
#pragma unroll
    for (int kc = 0; kc < 2; ++kc)
      qbf[j][kc] = *(const bf16x8*)(Qb + kvbase + (size_t)(q0 + j * 16 + li) * HDn + kc * 32 + g * 8);

  const int lr8 = lane >> 3, lc = lane & 7;
  const int xc8 = (lc ^ lr8) * 8;
  const unsigned short* src = Kb + kvbase + (size_t)(wave * 64 + lr8) * HDn + xc8;

#define STG(kb_, buf_)                                                        \
  do {                                                                        \
    _Pragma("unroll") for (int i = 0; i < 8; ++i)                             \
        gll16(src + (size_t)((kb_) + i * 8) * HDn, &KT[buf_][(wave * 64 + i * 8) * 64]); \
  } while (0)

  float dacc[4][4];
#pragma unroll
  for (int j = 0; j < 4; ++j)
#pragma unroll
    for (int r = 0; r < 4; ++r) dacc[j][r] = 0.f;

  STG(0, 0);
  __syncthreads();
  for (int t = 0; t < Sn / 128; ++t) {
    if (t + 1 < Sn / 128) STG((t + 1) * 128, (t + 1) & 1);
    const unsigned short* TK = &KT[t & 1][0];
#pragma unroll
    for (int nt = 0; nt < 8; ++nt) {
      const int krow = nt * 16 + li;
      const bf16x8 kf0 = FR(TK, krow, g), kf1 = FR(TK, krow, 4 + g);
#pragma unroll
      for (int j = 0; j < 4; ++j) {
        f32x4 s = Z4;
        s = MFMA(kf0, qbf[j][0], s);
        s = MFMA(kf1, qbf[j][1], s);
#pragma unroll
        for (int r = 0; r < 4; ++r) dacc[j][r] += EXP2(s[r]);
      }
    }
    __syncthreads();
  }
#pragma unroll
  for (int j = 0; j < 4; ++j) {
    float den = (dacc[j][0] + dacc[j][1]) + (dacc[j][2] + dacc[j][3]);
    den += __shfl_xor(den, 16);
    den += __shfl_xor(den, 32);
    if (lane < 16) Lbuf[bh * Sn + q0 + j * 16 + li] = LOG2(den) - C2;
  }
#undef STG
}

// ---------------------------------------------------------------------------
// 4. k_attn (pass B): folded (f, 31-f) blocks, G=2 (16+16 q per wave).
//    K LDS double-buffered; V fragments straight from L2 into regs (T14);
//    P per-wave in LDS; one barrier per tile. grid 512 (XCD-remapped).
// ---------------------------------------------------------------------------
__global__ __launch_bounds__(256, 2) void k_attn(
    const unsigned short* __restrict__ Qr, const unsigned short* __restrict__ Kr,
    const unsigned short* __restrict__ Vt, const float* __restrict__ Lbuf,
    unsigned short* __restrict__ Zb) {
  __shared__ unsigned short KT[2][64 * 64];  // 16 KB Kr tile dbuf
  __shared__ unsigned short Pl[4][2][1024];  // 16 KB per-wave P (L,H)

  const int tid = threadIdx.x;
  const int wave = tid >> 6, lane = tid & 63, g = lane >> 4, li = lane & 15;
  const int raw = blockIdx.x;  // 512; remap for per-XCD bh locality
  const int xcd = raw & 7, idx = raw >> 3;
  const int bh = xcd * 4 + (idx >> 4);
  const int f = idx & 15;
  const int tL = f, tH = 31 - f;
  const int qwL = tL * 64 + wave * 16, qwH = tH * 64 + wave * 16;
  const size_t kvbase = (size_t)bh * (Sn * HDn);

  bf16x8 qrfL[2], qrfH[2];
#pragma unroll
  for (int kc = 0; kc < 2; ++kc) {
    qrfL[kc] = *(const bf16x8*)(Qr + kvbase + (size_t)(qwL + li) * HDn + kc * 32 + g * 8);
    qrfH[kc] = *(const bf16x8*)(Qr + kvbase + (size_t)(qwH + li) * HDn + kc * 32 + g * 8);
  }
  const float mLcL = -Lbuf[bh * Sn + qwL + li];
  const float mLcH = -Lbuf[bh * Sn + qwH + li];

  const int lr8 = lane >> 3, lc = lane & 7;
  const int xc8 = (lc ^ lr8) * 8;
  const unsigned short* srcK = Kr + kvbase + (size_t)(wave * 16 + lr8) * HDn + xc8;

#define STGK(kb_, buf_)                                                      \
  do {                                                                       \
    gll16(srcK + (size_t)(kb_)*HDn, &KT[buf_][(wave * 16) * 64]);            \
    gll16(srcK + (size_t)((kb_) + 8) * HDn, &KT[buf_][(wave * 16 + 8) * 64]); \
  } while (0)

  const unsigned short* vp0 = Vt + kvbase + (size_t)(0 * 16 + li) * Sn + g * 8;
  const unsigned short* vp1 = Vt + kvbase + (size_t)(1 * 16 + li) * Sn + g * 8;
  const unsigned short* vp2 = Vt + kvbase + (size_t)(2 * 16 + li) * Sn + g * 8;
  const unsigned short* vp3 = Vt + kvbase + (size_t)(3 * 16 + li) * Sn + g * 8;

  unsigned short* myPL = &Pl[wave][0][0];
  unsigned short* myPH = &Pl[wave][1][0];

  f32x4 acczL[4], acczH[4];
#pragma unroll
  for (int i = 0; i < 4; ++i) {
    acczL[i] = Z4;
    acczH[i] = Z4;
  }
  float wsL[4] = {0.f, 0.f, 0.f, 0.f}, wsH[4] = {0.f, 0.f, 0.f, 0.f};
  bool dm[4];
#pragma unroll
  for (int r = 0; r < 4; ++r) dm[r] = (4 * g + r) <= li;

  STGK(0, 0);
  __syncthreads();
  for (int t = 0; t <= tH; ++t) {
    if (t < tH) STGK((t + 1) * 64, (t + 1) & 1);
    // V fragments for THIS tile straight from global (L2-resident), early issue
    bf16x8 v00 = *(const bf16x8*)(vp0 + t * 64);
    bf16x8 v01 = *(const bf16x8*)(vp1 + t * 64);
    bf16x8 v02 = *(const bf16x8*)(vp2 + t * 64);
    bf16x8 v03 = *(const bf16x8*)(vp3 + t * 64);
    bf16x8 v10 = *(const bf16x8*)(vp0 + t * 64 + 32);
    bf16x8 v11 = *(const bf16x8*)(vp1 + t * 64 + 32);
    bf16x8 v12 = *(const bf16x8*)(vp2 + t * 64 + 32);
    bf16x8 v13 = *(const bf16x8*)(vp3 + t * 64 + 32);

    const unsigned short* T0 = &KT[t & 1][0];
    const bool loAct = (t <= tL);
#pragma unroll
    for (int nt = 0; nt < 4; ++nt) {
      const int krow = nt * 16 + li;
      const bf16x8 kf0 = FR(T0, krow, g), kf1 = FR(T0, krow, 4 + g);
      const int adr = li * 64 + (((nt * 2 + (g >> 1)) ^ (li & 7)) * 8) + (g & 1) * 4;
      // ---- H group ----
      {
        float w[4];
        if (t < tH || nt <= wave) {
          f32x4 s = {mLcH, mLcH, mLcH, mLcH};
          s = MFMA(kf0, qrfH[0], s);
          s = MFMA(kf1, qrfH[1], s);
          if (t == tH && nt == wave) {
#pragma unroll
            for (int r = 0; r < 4; ++r) {
              const float e = EXP2(EXP2(s[r]));
              w[r] = dm[r] ? e : 0.f;
            }
          } else {
#pragma unroll
            for (int r = 0; r < 4; ++r) w[r] = EXP2(EXP2(s[r]));
          }
#pragma unroll
          for (int r = 0; r < 4; ++r) wsH[r] += w[r];
        } else {
          w[0] = w[1] = w[2] = w[3] = 0.f;
        }
        *(uint2*)&myPH[adr] = (uint2){cvtpk(w[0], w[1]), cvtpk(w[2], w[3])};
      }
      // ---- L group ----
      if (loAct) {
        float w[4];
        if (t < tL || nt <= wave) {
          f32x4 s = {mLcL, mLcL, mLcL, mLcL};
          s = MFMA(kf0, qrfL[0], s);
          s = MFMA(kf1, qrfL[1], s);
          if (t == tL && nt == wave) {
#pragma unroll
            for (int r = 0; r < 4; ++r) {
              const float e = EXP2(EXP2(s[r]));
              w[r] = dm[r] ? e : 0.f;
            }
          } else {
#pragma unroll
            for (int r = 0; r < 4; ++r) w[r] = EXP2(EXP2(s[r]));
          }
#pragma unroll
          for (int r = 0; r < 4; ++r) wsL[r] += w[r];
        } else {
          w[0] = w[1] = w[2] = w[3] = 0.f;
        }
        *(uint2*)&myPL[adr] = (uint2){cvtpk(w[0], w[1]), cvtpk(w[2], w[3])};
      }
    }
    // ---- PV (V regs shared by both groups) ----
    {
      const bf16x8 paH0 = FR(myPH, li, 0 + g), paH1 = FR(myPH, li, 4 + g);
      acczH[0] = MFMA(paH0, v00, acczH[0]);
      acczH[1] = MFMA(paH0, v01, acczH[1]);
      acczH[2] = MFMA(paH0, v02, acczH[2]);
      acczH[3] = MFMA(paH0, v03, acczH[3]);
      acczH[0] = MFMA(paH1, v10, acczH[0]);
      acczH[1] = MFMA(paH1, v11, acczH[1]);
      acczH[2] = MFMA(paH1, v12, acczH[2]);
      acczH[3] = MFMA(paH1, v13, acczH[3]);
      if (loAct) {
        const bf16x8 paL0 = FR(myPL, li, 0 + g), paL1 = FR(myPL, li, 4 + g);
        acczL[0] = MFMA(paL0, v00, acczL[0]);
        acczL[1] = MFMA(paL0, v01, acczL[1]);
        acczL[2] = MFMA(paL0, v02, acczL[2]);
        acczL[3] = MFMA(paL0, v03, acczL[3]);
        acczL[0] = MFMA(paL1, v10, acczL[0]);
        acczL[1] = MFMA(paL1, v11, acczL[1]);
        acczL[2] = MFMA(paL1, v12, acczL[2]);
        acczL[3] = MFMA(paL1, v13, acczL[3]);
      }
    }
    __syncthreads();
  }

  // normalize + write bf16 [b*S+q][H*HD]
  float wsumL = (wsL[0] + wsL[1]) + (wsL[2] + wsL[3]);
  float wsumH = (wsH[0] + wsH[1]) + (wsH[2] + wsH[3]);
  wsumL += __shfl_xor(wsumL, 16);
  wsumL += __shfl_xor(wsumL, 32);
  wsumH += __shfl_xor(wsumH, 16);
  wsumH += __shfl_xor(wsumH, 32);
  float rwL[4], rwH[4];
#pragma unroll
  for (int r = 0; r < 4; ++r) {
    rwL[r] = 1.f / __shfl(wsumL, 4 * g + r);
    rwH[r] = 1.f / __shfl(wsumH, 4 * g + r);
  }
  const int b = bh >> 4, h = bh & 15;
#pragma unroll
  for (int n2 = 0; n2 < 4; ++n2) {
#pragma unroll
    for (int r = 0; r < 4; ++r) {
      const int hd = n2 * 16 + li;
      Zb[((size_t)(b * Sn + qwL + 4 * g + r)) * Dn + h * HDn + hd] = f2bf(acczL[n2][r] * rwL[r]);
      Zb[((size_t)(b * Sn + qwH + 4 * g + r)) * Dn + h * HDn + hd] = f2bf(acczH[n2][r] * rwH[r]);
    }
  }
#undef STGK
}

// ---------------------------------------------------------------------------
extern "C" void kernel_launch(void* const* d_in, const int* in_sizes, int n_in,
                              void* d_out, int out_size, void* d_ws, size_t ws_size,
                              hipStream_t stream) {
  const float* query = (const float*)d_in[0];
  const float* key   = (const float*)d_in[1];
  const float* value = (const float*)d_in[2];
  const float* Wq = (const float*)d_in[4];
  const float* bq = (const float*)d_in[5];
  const float* Wk = (const float*)d_in[6];
  const float* bk = (const float*)d_in[7];
  const float* Wv = (const float*)d_in[8];
  const float* bv = (const float*)d_in[9];
  const float* Wo = (const float*)d_in[10];
  const float* bo = (const float*)d_in[11];

  char* ws = (char*)d_ws;
  const size_t MB = 1ull << 20;
  unsigned short* Wqt = (unsigned short*)(ws + 0 * MB);
  unsigned short* Wkt = (unsigned short*)(ws + 2 * MB);
  unsigned short* Wvt = (unsigned short*)(ws + 4 * MB);
  unsigned short* Wot = (unsigned short*)(ws + 6 * MB);
  float2* trig        = (float2*)(ws + 8 * MB);             // 512 KB
  float* Lbuf         = (float*)(ws + 8 * MB + 512 * 1024); // 256 KB
  unsigned short* Qa  = (unsigned short*)(ws + 9 * MB);     // bf16 activations
  unsigned short* Ka  = (unsigned short*)(ws + 17 * MB);
  unsigned short* Va  = (unsigned short*)(ws + 25 * MB);
  unsigned short* Qb  = (unsigned short*)(ws + 33 * MB);    // [b,h,s,hd] (Q prescaled)
  unsigned short* Kb  = (unsigned short*)(ws + 41 * MB);
  unsigned short* Qr  = (unsigned short*)(ws + 49 * MB);
  unsigned short* Kr  = (unsigned short*)(ws + 57 * MB);
  unsigned short* Vt  = (unsigned short*)(ws + 65 * MB);    // [b,h,hd,s]
  unsigned short* Zb  = (unsigned short*)(ws + 73 * MB);    // [m][1024] bf16

  k_pre<<<7424, 256, 0, stream>>>(Wq, Wk, Wv, Wo, Wqt, Wkt, Wvt, Wot,
                                  query, key, value, Qa, Ka, Va, trig);
  k_gemm_proj<<<dim3(32, 8, 3), 256, 0, stream>>>(Qa, Ka, Va, Wqt, Wkt, Wvt,
                                                  bq, bk, bv, trig, Qb, Kb, Qr, Kr, Vt);
  k_den<<<512, 128, 0, stream>>>(Qb, Kb, Lbuf);
  k_attn<<<512, 256, 0, stream>>>(Qr, Kr, Vt, Lbuf, Zb);
  k_gemm_out<<<dim3(64, 8), 256, 0, stream>>>(Zb, Wot, bo, (float*)d_out);
}

// Round 9
// 150.310 us; speedup vs baseline: 1.2323x; 1.2323x over previous
//
#include <hip/hip_runtime.h>

// ---------------------------------------------------------------------------
// RoPE Multi-Headed Attention (quirky softmax(exp(qr·kr)/den) variant)
// B=2, S=2048, D=1024, H=16, HD=64
// Round 9 = recovery build: r6 k_pre + r5/r6 GEMMs + r5 k_attn (all verbatim,
// no s_setprio anywhere — prime suspect for r7/r8 correctness breaks).
// ---------------------------------------------------------------------------

#define Bn 2
#define Sn 2048
#define Dn 1024
#define Hn 16
#define HDn 64

typedef __attribute__((ext_vector_type(8))) short bf16x8;
typedef __attribute__((ext_vector_type(8))) unsigned short u16x8;
typedef __attribute__((ext_vector_type(4))) unsigned short u16x4;
typedef __attribute__((ext_vector_type(4))) float f32x4;

#define MFMA(a, b, c) __builtin_amdgcn_mfma_f32_16x16x32_bf16(a, b, c, 0, 0, 0)
#define Z4 ((f32x4){0.f, 0.f, 0.f, 0.f})

// 0.125 * log2(e): folds the 1/sqrt(HD) scale and the exp->exp2 change into Q
#define PRESC 0.18033688011112042f
// log2(log2(e)): A = a*log2(e) = 2^(s' - L2 + C2)
#define C2 0.5287663729448977f

#define EXP2(x) __builtin_amdgcn_exp2f(x)
#define LOG2(x) __builtin_amdgcn_logf(x)

__device__ __forceinline__ unsigned short f2bf(float f) {
  unsigned int u = __builtin_bit_cast(unsigned int, f);
  u = (u + 0x7fffu + ((u >> 16) & 1u)) >> 16;
  return (unsigned short)u;
}

__device__ __forceinline__ unsigned int cvtpk(float lo, float hi) {
  unsigned int r;
  asm("v_cvt_pk_bf16_f32 %0, %1, %2" : "=v"(r) : "v"(lo), "v"(hi));
  return r;
}

// async global->LDS, 16B per lane; dst is wave-uniform base (lane writes +lane*16B)
__device__ __forceinline__ void gll16(const unsigned short* g, unsigned short* l) {
  __builtin_amdgcn_global_load_lds((const __attribute__((address_space(1))) void*)g,
                                   (__attribute__((address_space(3))) void*)l, 16, 0, 0);
}

// swizzled fragment read: LDS slot c of row r holds source chunk c^(r&7)
#define FR(T, row, x) (*(const bf16x8*)&(T)[(row) * 64 + (((x) ^ ((row) & 7)) * 8)])

// ---------------------------------------------------------------------------
// 0. k_pre: merged trig table + weight transpose + activation convert.
//    blocks [0,256): trig; [256,1280): wtrans; [1280,7424): cvt
// ---------------------------------------------------------------------------
__global__ __launch_bounds__(256) void k_pre(
    const float* __restrict__ W0, const float* __restrict__ W1,
    const float* __restrict__ W2, const float* __restrict__ W3,
    unsigned short* __restrict__ O0, unsigned short* __restrict__ O1,
    unsigned short* __restrict__ O2, unsigned short* __restrict__ O3,
    const float* __restrict__ qa, const float* __restrict__ ka, const float* __restrict__ va,
    unsigned short* __restrict__ oq, unsigned short* __restrict__ ok,
    unsigned short* __restrict__ ov, float2* __restrict__ T) {
  __shared__ float t[64][65];
  const int b = blockIdx.x;
  const int tid = threadIdx.x;
  if (b < 256) {
    const int idx = b * 256 + tid;  // 65536
    const int s = idx >> 5, i = idx & 31;
    const float theta = powf(1000.f, -(float)i / 32.f);
    const float pm = (float)s * theta;
    T[idx] = make_float2(cosf(pm), sinf(pm));
  } else if (b < 1280) {
    const int w = b - 256;
    const int which = w >> 8, rem = w & 255;
    const float* W = (which == 0) ? W0 : (which == 1) ? W1 : (which == 2) ? W2 : W3;
    unsigned short* O = (which == 0) ? O0 : (which == 1) ? O1 : (which == 2) ? O2 : O3;
    const int kb = (rem >> 4) * 64, nb = (rem & 15) * 64;
#pragma unroll
    for (int rep = 0; rep < 16; ++rep) {
      const int e = rep * 256 + tid;
      const int k = e >> 6, n = e & 63;
      t[k][n] = W[(kb + k) * Dn + nb + n];
    }
    __syncthreads();
#pragma unroll
    for (int rep = 0; rep < 16; ++rep) {
      const int e = rep * 256 + tid;
      const int n = e >> 6, k = e & 63;
      O[(nb + n) * Dn + kb + k] = f2bf(t[k][n]);
    }
  } else {
    const int c = b - 1280;  // 6144 blocks
    const int z = c >> 11, cx = c & 2047;
    const float* s = (z == 0) ? qa : (z == 1) ? ka : va;
    unsigned short* d = (z == 0) ? oq : (z == 1) ? ok : ov;
    const size_t idx = ((size_t)cx * 256 + tid) * 8;
    float4 a0 = *(const float4*)(s + idx);
    float4 b0 = *(const float4*)(s + idx + 4);
    u16x8 pk;
    pk[0] = f2bf(a0.x); pk[1] = f2bf(a0.y); pk[2] = f2bf(a0.z); pk[3] = f2bf(a0.w);
    pk[4] = f2bf(b0.x); pk[5] = f2bf(b0.y); pk[6] = f2bf(b0.z); pk[7] = f2bf(b0.w);
    *(u16x8*)(d + idx) = pk;
  }
}

// ---------------------------------------------------------------------------
// 1. Fused QKV projection GEMM (gll-staged). grid (32, 8, 3); z = {Q,K,V}.
//    Q: prescaled by PRESC; Q/K write base + roped; V writes Vt [b,h,hd,s].
// ---------------------------------------------------------------------------
__global__ __launch_bounds__(256) void k_gemm_proj(
    const unsigned short* __restrict__ Qa, const unsigned short* __restrict__ Ka,
    const unsigned short* __restrict__ Va,
    const unsigned short* __restrict__ Wq, const unsigned short* __restrict__ Wk,
    const unsigned short* __restrict__ Wv,
    const float* __restrict__ bqp, const float* __restrict__ bkp, const float* __restrict__ bvp,
    const float2* __restrict__ trig,
    unsigned short* __restrict__ Qb, unsigned short* __restrict__ Kb,
    unsigned short* __restrict__ Qr, unsigned short* __restrict__ Kr,
    unsigned short* __restrict__ Vt) {
  __shared__ unsigned short Al[128 * 64];
  __shared__ unsigned short Bl[128 * 64];
  const int tid = threadIdx.x;
  const int wave = tid >> 6, lane = tid & 63, g = lane >> 4, li = lane & 15;
  const int mbase = blockIdx.x * 128, nbase = blockIdx.y * 128;
  const int wm = wave >> 1, wn = wave & 1;
  const int which = blockIdx.z;
  const unsigned short* A = (which == 0) ? Qa : (which == 1) ? Ka : Va;
  const unsigned short* Wt = (which == 0) ? Wq : (which == 1) ? Wk : Wv;
  const float* bias = (which == 0) ? bqp : (which == 1) ? bkp : bvp;

  f32x4 acc[4][4];
#pragma unroll
  for (int i = 0; i < 4; ++i)
#pragma unroll
    for (int j = 0; j < 4; ++j) acc[i][j] = Z4;

  float bv4[4];
#pragma unroll
  for (int nt = 0; nt < 4; ++nt) bv4[nt] = bias[nbase + wn * 64 + nt * 16 + li];

  const int lr8 = lane >> 3, lc = lane & 7;
  const int xc8 = (lc ^ lr8) * 8;
  const unsigned short* srcA = A + (size_t)(mbase + wave * 32 + lr8) * Dn + xc8;
  const unsigned short* srcB = Wt + (size_t)(nbase + wave * 32 + lr8) * Dn + xc8;

  for (int kb = 0; kb < Dn; kb += 64) {
    __syncthreads();
#pragma unroll
    for (int i = 0; i < 4; ++i) {
      gll16(srcA + kb + (size_t)i * (8 * Dn), &Al[(wave * 32 + i * 8) * 64]);
      gll16(srcB + kb + (size_t)i * (8 * Dn), &Bl[(wave * 32 + i * 8) * 64]);
    }
    __syncthreads();
#pragma unroll
    for (int kc = 0; kc < 2; ++kc) {
      bf16x8 af[4], bfr[4];
#pragma unroll
      for (int mt = 0; mt < 4; ++mt) af[mt] = FR(Al, wm * 64 + mt * 16 + li, kc * 4 + g);
#pragma unroll
      for (int nt = 0; nt < 4; ++nt) bfr[nt] = FR(Bl, wn * 64 + nt * 16 + li, kc * 4 + g);
#pragma unroll
      for (int mt = 0; mt < 4; ++mt)
#pragma unroll
        for (int nt = 0; nt < 4; ++nt)
          acc[mt][nt] = MFMA(af[mt], bfr[nt], acc[mt][nt]);
    }
  }

  if (which < 2) {
    unsigned short* Ob = (which == 0) ? Qb : Kb;
    unsigned short* Or = (which == 0) ? Qr : Kr;
    const float presc = (which == 0) ? PRESC : 1.f;
#pragma unroll
    for (int mt = 0; mt < 4; ++mt) {
#pragma unroll
      for (int nt = 0; nt < 4; ++nt) {
        const int n = nbase + wn * 64 + nt * 16 + li;
        const int h = n >> 6, hd = n & 63;
        const int ti = hd >> 1;
        const float sgn = (hd & 1) ? 1.f : -1.f;
#pragma unroll
        for (int r = 0; r < 4; ++r) {
          const int m = mbase + wm * 64 + mt * 16 + 4 * g + r;
          const int b = m >> 11, s = m & (Sn - 1);
          const float v = (acc[mt][nt][r] + bv4[nt]) * presc;
          const size_t oi = (((size_t)(b * Hn + h)) * Sn + s) * HDn + hd;
          Ob[oi] = f2bf(v);
          const float p = __shfl_xor(v, 1);
          const float2 cs = trig[(s << 5) + ti];
          Or[oi] = f2bf(fmaf(sgn * p, cs.y, v * cs.x));
        }
      }
    }
  } else {
#pragma unroll
    for (int mt = 0; mt < 4; ++mt) {
#pragma unroll
      for (int nt = 0; nt < 4; ++nt) {
        const int n = nbase + wn * 64 + nt * 16 + li;
        const int h = n >> 6, hd = n & 63;
        const int m0 = mbase + wm * 64 + mt * 16 + 4 * g;
        const int b = m0 >> 11, s0 = m0 & (Sn - 1);
        u16x4 pk;
#pragma unroll
        for (int r = 0; r < 4; ++r) pk[r] = f2bf(acc[mt][nt][r] + bv4[nt]);
        *(u16x4*)&Vt[(((size_t)(b * Hn + h)) * HDn + hd) * Sn + s0] = pk;
      }
    }
  }
}

// ---------------------------------------------------------------------------
// 2. Output GEMM 64x128 tile (gll-staged): A bf16 [4096][1024], out f32 + bias
// ---------------------------------------------------------------------------
__global__ __launch_bounds__(256) void k_gemm_out(const unsigned short* __restrict__ A,
                                                  const unsigned short* __restrict__ Wt,
                                                  const float* __restrict__ bias,
                                                  float* __restrict__ out) {
  __shared__ unsigned short Al[64 * 64];
  __shared__ unsigned short Bl[128 * 64];
  const int tid = threadIdx.x;
  const int wave = tid >> 6, lane = tid & 63, g = lane >> 4, li = lane & 15;
  const int mbase = blockIdx.x * 64, nbase = blockIdx.y * 128;
  const int wm = wave >> 1, wn = wave & 1;

  f32x4 acc[2][4];
#pragma unroll
  for (int i = 0; i < 2; ++i)
#pragma unroll
    for (int j = 0; j < 4; ++j) acc[i][j] = Z4;

  float bv4[4];
#pragma unroll
  for (int nt = 0; nt < 4; ++nt) bv4[nt] = bias[nbase + wn * 64 + nt * 16 + li];

  const int lr8 = lane >> 3, lc = lane & 7;
  const int xc8 = (lc ^ lr8) * 8;
  const unsigned short* srcA = A + (size_t)(mbase + wave * 16 + lr8) * Dn + xc8;
  const unsigned short* srcB = Wt + (size_t)(nbase + wave * 32 + lr8) * Dn + xc8;

  for (int kb = 0; kb < Dn; kb += 64) {
    __syncthreads();
#pragma unroll
    for (int i = 0; i < 2; ++i)
      gll16(srcA + kb + (size_t)i * (8 * Dn), &Al[(wave * 16 + i * 8) * 64]);
#pragma unroll
    for (int i = 0; i < 4; ++i)
      gll16(srcB + kb + (size_t)i * (8 * Dn), &Bl[(wave * 32 + i * 8) * 64]);
    __syncthreads();
#pragma unroll
    for (int kc = 0; kc < 2; ++kc) {
      bf16x8 af[2], bfr[4];
#pragma unroll
      for (int mt = 0; mt < 2; ++mt) af[mt] = FR(Al, wm * 32 + mt * 16 + li, kc * 4 + g);
#pragma unroll
      for (int nt = 0; nt < 4; ++nt) bfr[nt] = FR(Bl, wn * 64 + nt * 16 + li, kc * 4 + g);
#pragma unroll
      for (int mt = 0; mt < 2; ++mt)
#pragma unroll
        for (int nt = 0; nt < 4; ++nt)
          acc[mt][nt] = MFMA(af[mt], bfr[nt], acc[mt][nt]);
    }
  }

#pragma unroll
  for (int mt = 0; mt < 2; ++mt)
#pragma unroll
    for (int nt = 0; nt < 4; ++nt) {
      const int n = nbase + wn * 64 + nt * 16 + li;
#pragma unroll
      for (int r = 0; r < 4; ++r) {
        const int m = mbase + wm * 32 + mt * 16 + 4 * g + r;
        out[(size_t)m * Dn + n] = acc[mt][nt][r] + bv4[nt];
      }
    }
}

// ---------------------------------------------------------------------------
// 3. Attention (round-5 verbatim). grid 1024 blocks (balanced qt map),
//    4 waves x 16 q-rows each. Swapped QK^T, exp2 algebra, no max tracking.
//    LDS 40 KB -> 4 blocks/CU, 4 waves/SIMD.
// ---------------------------------------------------------------------------
__global__ __launch_bounds__(256, 4) void k_attn(
    const unsigned short* __restrict__ Qr, const unsigned short* __restrict__ Kr,
    const unsigned short* __restrict__ Qb, const unsigned short* __restrict__ Kb,
    const unsigned short* __restrict__ Vt, unsigned short* __restrict__ Zb) {
  __shared__ unsigned short KT[2][8192];  // 32 KB: passA = 128x64 Kb; passB = [Kr 64x64 | Vt 64x64]
  __shared__ unsigned short Pl[4][1024];  // 8 KB per-wave P [q][k] swizzled

  const int tid = threadIdx.x;
  const int wave = tid >> 6, lane = tid & 63, g = lane >> 4, li = lane & 15;
  // balanced qt assignment: any 4 consecutive bids have qt summing to 62
  const int bid = blockIdx.x;
  const int i4 = bid & 3, j = bid >> 2;
  const int bh = j & 31, grp = j >> 5;  // grp 0..7
  const int qt = (i4 == 0) ? grp : (i4 == 1) ? 15 - grp : (i4 == 2) ? 16 + grp : 31 - grp;
  const int qw = qt * 64 + wave * 16;
  const size_t kvbase = (size_t)bh * (Sn * HDn);

  // Q fragments (prescaled by PRESC at projection)
  bf16x8 qrf[2], qbf[2];
#pragma unroll
  for (int kc = 0; kc < 2; ++kc) {
    const size_t a = kvbase + (size_t)(qw + li) * HDn + kc * 32 + g * 8;
    qrf[kc] = *(const bf16x8*)(Qr + a);
    qbf[kc] = *(const bf16x8*)(Qb + a);
  }

  const int lr8 = lane >> 3, lc = lane & 7;
  const int xc8 = (lc ^ lr8) * 8;  // source-side swizzle

  // pass A: whole block stages one 128x64 Kb tile; wave covers rows wave*32..+31
  const unsigned short* srcPA = Kb + kvbase + (size_t)(wave * 32 + lr8) * HDn + xc8;
  // pass B: tw = tensor (0=Kr rows k, 1=Vt rows hd), rbB = row base
  const int tw = wave >> 1, rbB = (wave & 1) * 32;
  const unsigned short* srcKrB = Kr + kvbase + (size_t)(rbB + lr8) * HDn + xc8;
  const unsigned short* srcVtB = Vt + kvbase + (size_t)(rbB + lr8) * Sn + xc8;
  const size_t strIB = tw ? (size_t)(8 * Sn) : (size_t)(8 * HDn);
  unsigned short* myP = &Pl[wave][0];

  // diag masks: k-offset 4g+r causal-valid vs q-offset li (tile-invariant)
  bool dm[4];
#pragma unroll
  for (int r = 0; r < 4; ++r) dm[r] = (4 * g + r) <= li;

#define STAGE_PA(kb_, buf_)                                 \
  do {                                                      \
    unsigned short* d_ = &KT[buf_][(wave * 32) * 64];       \
    const unsigned short* s_ = srcPA + (size_t)(kb_)*HDn;   \
    gll16(s_, d_);                                          \
    gll16(s_ + 8 * HDn, d_ + 8 * 64);                       \
    gll16(s_ + 16 * HDn, d_ + 16 * 64);                     \
    gll16(s_ + 24 * HDn, d_ + 24 * 64);                     \
  } while (0)

#define STAGE_B(kb_, buf_)                                                    \
  do {                                                                        \
    unsigned short* d_ = &KT[buf_][tw * 4096 + rbB * 64];                     \
    const unsigned short* s_ =                                                \
        tw ? (srcVtB + (size_t)(kb_)) : (srcKrB + (size_t)(kb_)*HDn);         \
    gll16(s_, d_);                                                            \
    gll16(s_ + strIB, d_ + 8 * 64);                                           \
    gll16(s_ + 2 * strIB, d_ + 16 * 64);                                      \
    gll16(s_ + 3 * strIB, d_ + 24 * 64);                                      \
  } while (0)

  // ------------------- PASS A: den = sum over ALL k of 2^(s') -------------------
  float d4[4] = {0.f, 0.f, 0.f, 0.f};
  STAGE_PA(0, 0);
  __syncthreads();
  for (int t = 0; t < Sn / 128; ++t) {
    if (t + 1 < Sn / 128) STAGE_PA((t + 1) * 128, (t + 1) & 1);
    const unsigned short* TK = &KT[t & 1][0];
#pragma unroll
    for (int nt = 0; nt < 8; ++nt) {
      const int krow = nt * 16 + li;
      const bf16x8 kf0 = FR(TK, krow, g), kf1 = FR(TK, krow, 4 + g);
      f32x4 s = Z4;
      s = MFMA(kf0, qbf[0], s);
      s = MFMA(kf1, qbf[1], s);
#pragma unroll
      for (int r = 0; r < 4; ++r) d4[r] += EXP2(s[r]);
    }
    __syncthreads();
  }
  float den = (d4[0] + d4[1]) + (d4[2] + d4[3]);
  den += __shfl_xor(den, 16);
  den += __shfl_xor(den, 32);
  const float Lc = LOG2(den) - C2;  // lane's q = qw+li; A = 2^(s' - Lc)
  const f32x4 mLc = {-Lc, -Lc, -Lc, -Lc};

  // ------------------- PASS B: w = 2^A (no max; A bounded), Z = P.V -------------
  f32x4 accz[4];
#pragma unroll
  for (int i = 0; i < 4; ++i) accz[i] = Z4;
  float ws[4] = {0.f, 0.f, 0.f, 0.f};
  const int NTB = qt + 1;

  STAGE_B(0, 0);
  __syncthreads();
  for (int t = 0; t < NTB; ++t) {
    if (t + 1 < NTB) STAGE_B((t + 1) * 64, (t + 1) & 1);
    const unsigned short* T0 = &KT[t & 1][0];         // Kr [k][hd]
    const unsigned short* TV = &KT[t & 1][0] + 4096;  // Vt [hd][k]
    const bool last = (t == qt);
#pragma unroll
    for (int nt = 0; nt < 4; ++nt) {
      float w[4];
      if (!last || nt <= wave) {
        const int krow = nt * 16 + li;
        const bf16x8 kf0 = FR(T0, krow, g), kf1 = FR(T0, krow, 4 + g);
        f32x4 s = mLc;
        s = MFMA(kf0, qrf[0], s);
        s = MFMA(kf1, qrf[1], s);
        if (last && nt == wave) {  // diagonal subtile
#pragma unroll
          for (int r = 0; r < 4; ++r) {
            const float e = EXP2(EXP2(s[r]));
            w[r] = dm[r] ? e : 0.f;
            ws[r] += w[r];
          }
        } else {
#pragma unroll
          for (int r = 0; r < 4; ++r) {
            w[r] = EXP2(EXP2(s[r]));
            ws[r] += w[r];
          }
        }
      } else {
        w[0] = w[1] = w[2] = w[3] = 0.f;
      }
      const int adr = li * 64 + (((nt * 2 + (g >> 1)) ^ (li & 7)) * 8) + (g & 1) * 4;
      *(uint2*)&myP[adr] = (uint2){cvtpk(w[0], w[1]), cvtpk(w[2], w[3])};
    }
    // PV: accz[n2] = Z[q = qw+4g+r][hd = n2*16+li]
#pragma unroll
    for (int kc = 0; kc < 2; ++kc) {
      const bf16x8 pa = FR(myP, li, kc * 4 + g);
#pragma unroll
      for (int n2 = 0; n2 < 4; ++n2) {
        const bf16x8 vb = FR(TV, n2 * 16 + li, kc * 4 + g);
        accz[n2] = MFMA(pa, vb, accz[n2]);
      }
    }
    __syncthreads();
  }

  // normalize + write bf16 [b*S+q][H*HD]
  float wsum = (ws[0] + ws[1]) + (ws[2] + ws[3]);
  wsum += __shfl_xor(wsum, 16);
  wsum += __shfl_xor(wsum, 32);  // lane holds wsum for q = qw+li
  float rw[4];
#pragma unroll
  for (int r = 0; r < 4; ++r) rw[r] = 1.f / __shfl(wsum, 4 * g + r);
  const int b = bh >> 4, h = bh & 15;
#pragma unroll
  for (int n2 = 0; n2 < 4; ++n2) {
#pragma unroll
    for (int r = 0; r < 4; ++r) {
      const int hd = n2 * 16 + li;
      const int q = qw + 4 * g + r;
      Zb[((size_t)(b * Sn + q)) * Dn + h * HDn + hd] = f2bf(accz[n2][r] * rw[r]);
    }
  }
#undef STAGE_PA
#undef STAGE_B
}

// ---------------------------------------------------------------------------
extern "C" void kernel_launch(void* const* d_in, const int* in_sizes, int n_in,
                              void* d_out, int out_size, void* d_ws, size_t ws_size,
                              hipStream_t stream) {
  const float* query = (const float*)d_in[0];
  const float* key   = (const float*)d_in[1];
  const float* value = (const float*)d_in[2];
  const float* Wq = (const float*)d_in[4];
  const float* bq = (const float*)d_in[5];
  const float* Wk = (const float*)d_in[6];
  const float* bk = (const float*)d_in[7];
  const float* Wv = (const float*)d_in[8];
  const float* bv = (const float*)d_in[9];
  const float* Wo = (const float*)d_in[10];
  const float* bo = (const float*)d_in[11];

  char* ws = (char*)d_ws;
  const size_t MB = 1ull << 20;
  unsigned short* Wqt = (unsigned short*)(ws + 0 * MB);
  unsigned short* Wkt = (unsigned short*)(ws + 2 * MB);
  unsigned short* Wvt = (unsigned short*)(ws + 4 * MB);
  unsigned short* Wot = (unsigned short*)(ws + 6 * MB);
  float2* trig        = (float2*)(ws + 8 * MB);           // 512 KB
  unsigned short* Qa  = (unsigned short*)(ws + 9 * MB);   // bf16 activations
  unsigned short* Ka  = (unsigned short*)(ws + 17 * MB);
  unsigned short* Va  = (unsigned short*)(ws + 25 * MB);
  unsigned short* Qb  = (unsigned short*)(ws + 33 * MB);  // [b,h,s,hd] (Q prescaled)
  unsigned short* Kb  = (unsigned short*)(ws + 41 * MB);
  unsigned short* Qr  = (unsigned short*)(ws + 49 * MB);
  unsigned short* Kr  = (unsigned short*)(ws + 57 * MB);
  unsigned short* Vt  = (unsigned short*)(ws + 65 * MB);  // [b,h,hd,s]
  unsigned short* Zb  = (unsigned short*)(ws + 73 * MB);  // [m][1024] bf16

  k_pre<<<7424, 256, 0, stream>>>(Wq, Wk, Wv, Wo, Wqt, Wkt, Wvt, Wot,
                                  query, key, value, Qa, Ka, Va, trig);
  k_gemm_proj<<<dim3(32, 8, 3), 256, 0, stream>>>(Qa, Ka, Va, Wqt, Wkt, Wvt,
                                                  bq, bk, bv, trig, Qb, Kb, Qr, Kr, Vt);
  k_attn<<<1024, 256, 0, stream>>>(Qr, Kr, Qb, Kb, Vt, Zb);
  k_gemm_out<<<dim3(64, 8), 256, 0, stream>>>(Zb, Wot, bo, (float*)d_out);
}

// Round 11
// 136.769 us; speedup vs baseline: 1.3543x; 1.0990x over previous
//
#include <hip/hip_runtime.h>

// ---------------------------------------------------------------------------
// RoPE Multi-Headed Attention (quirky softmax(exp(qr·kr)/den) variant)
// B=2, S=2048, D=1024, H=16, HD=64
// Round 11 = round 9 (green) + TWO deltas:
//  (1) FIX latent TBAA race: P-tile LDS store was uint2* (int family) while
//      the PV read is bf16x8* (short family) with no intervening barrier —
//      compiler may legally reorder the read above the store. Store now goes
//      through a may_alias type + sched_barrier(0) fence. (Explains the
//      ~0.16 absmax failures of r7/r8/r10: recompilation flipped the order.)
//  (2) stride-256-balanced bid map (bijective => work-neutral): CU residents
//      {b,b+256,b+512,b+768} get qt {v,15-v,16+v,31-v} (uniform cost) and one
//      bh; XCD x=bid&7 sees only bh in [4x,4x+4) (K/V L2-resident).
// ---------------------------------------------------------------------------

#define Bn 2
#define Sn 2048
#define Dn 1024
#define Hn 16
#define HDn 64

typedef __attribute__((ext_vector_type(8))) short bf16x8;
typedef __attribute__((ext_vector_type(8))) unsigned short u16x8;
typedef __attribute__((ext_vector_type(4))) unsigned short u16x4;
typedef __attribute__((ext_vector_type(4))) float f32x4;
typedef uint2 __attribute__((may_alias)) uint2a;  // aliases everything: orders LDS P-store vs reads

#define MFMA(a, b, c) __builtin_amdgcn_mfma_f32_16x16x32_bf16(a, b, c, 0, 0, 0)
#define Z4 ((f32x4){0.f, 0.f, 0.f, 0.f})

// 0.125 * log2(e): folds the 1/sqrt(HD) scale and the exp->exp2 change into Q
#define PRESC 0.18033688011112042f
// log2(log2(e)): A = a*log2(e) = 2^(s' - L2 + C2)
#define C2 0.5287663729448977f

#define EXP2(x) __builtin_amdgcn_exp2f(x)
#define LOG2(x) __builtin_amdgcn_logf(x)

__device__ __forceinline__ unsigned short f2bf(float f) {
  unsigned int u = __builtin_bit_cast(unsigned int, f);
  u = (u + 0x7fffu + ((u >> 16) & 1u)) >> 16;
  return (unsigned short)u;
}

__device__ __forceinline__ unsigned int cvtpk(float lo, float hi) {
  unsigned int r;
  asm("v_cvt_pk_bf16_f32 %0, %1, %2" : "=v"(r) : "v"(lo), "v"(hi));
  return r;
}

// async global->LDS, 16B per lane; dst is wave-uniform base (lane writes +lane*16B)
__device__ __forceinline__ void gll16(const unsigned short* g, unsigned short* l) {
  __builtin_amdgcn_global_load_lds((const __attribute__((address_space(1))) void*)g,
                                   (__attribute__((address_space(3))) void*)l, 16, 0, 0);
}

// swizzled fragment read: LDS slot c of row r holds source chunk c^(r&7)
#define FR(T, row, x) (*(const bf16x8*)&(T)[(row) * 64 + (((x) ^ ((row) & 7)) * 8)])

// ---------------------------------------------------------------------------
// 0. k_pre: merged trig table + weight transpose + activation convert.
//    blocks [0,256): trig; [256,1280): wtrans; [1280,7424): cvt
// ---------------------------------------------------------------------------
__global__ __launch_bounds__(256) void k_pre(
    const float* __restrict__ W0, const float* __restrict__ W1,
    const float* __restrict__ W2, const float* __restrict__ W3,
    unsigned short* __restrict__ O0, unsigned short* __restrict__ O1,
    unsigned short* __restrict__ O2, unsigned short* __restrict__ O3,
    const float* __restrict__ qa, const float* __restrict__ ka, const float* __restrict__ va,
    unsigned short* __restrict__ oq, unsigned short* __restrict__ ok,
    unsigned short* __restrict__ ov, float2* __restrict__ T) {
  __shared__ float t[64][65];
  const int b = blockIdx.x;
  const int tid = threadIdx.x;
  if (b < 256) {
    const int idx = b * 256 + tid;  // 65536
    const int s = idx >> 5, i = idx & 31;
    const float theta = powf(1000.f, -(float)i / 32.f);
    const float pm = (float)s * theta;
    T[idx] = make_float2(cosf(pm), sinf(pm));
  } else if (b < 1280) {
    const int w = b - 256;
    const int which = w >> 8, rem = w & 255;
    const float* W = (which == 0) ? W0 : (which == 1) ? W1 : (which == 2) ? W2 : W3;
    unsigned short* O = (which == 0) ? O0 : (which == 1) ? O1 : (which == 2) ? O2 : O3;
    const int kb = (rem >> 4) * 64, nb = (rem & 15) * 64;
#pragma unroll
    for (int rep = 0; rep < 16; ++rep) {
      const int e = rep * 256 + tid;
      const int k = e >> 6, n = e & 63;
      t[k][n] = W[(kb + k) * Dn + nb + n];
    }
    __syncthreads();
#pragma unroll
    for (int rep = 0; rep < 16; ++rep) {
      const int e = rep * 256 + tid;
      const int n = e >> 6, k = e & 63;
      O[(nb + n) * Dn + kb + k] = f2bf(t[k][n]);
    }
  } else {
    const int c = b - 1280;  // 6144 blocks
    const int z = c >> 11, cx = c & 2047;
    const float* s = (z == 0) ? qa : (z == 1) ? ka : va;
    unsigned short* d = (z == 0) ? oq : (z == 1) ? ok : ov;
    const size_t idx = ((size_t)cx * 256 + tid) * 8;
    float4 a0 = *(const float4*)(s + idx);
    float4 b0 = *(const float4*)(s + idx + 4);
    u16x8 pk;
    pk[0] = f2bf(a0.x); pk[1] = f2bf(a0.y); pk[2] = f2bf(a0.z); pk[3] = f2bf(a0.w);
    pk[4] = f2bf(b0.x); pk[5] = f2bf(b0.y); pk[6] = f2bf(b0.z); pk[7] = f2bf(b0.w);
    *(u16x8*)(d + idx) = pk;
  }
}

// ---------------------------------------------------------------------------
// 1. Fused QKV projection GEMM (gll-staged). grid (32, 8, 3); z = {Q,K,V}.
//    Q: prescaled by PRESC; Q/K write base + roped; V writes Vt [b,h,hd,s].
// ---------------------------------------------------------------------------
__global__ __launch_bounds__(256) void k_gemm_proj(
    const unsigned short* __restrict__ Qa, const unsigned short* __restrict__ Ka,
    const unsigned short* __restrict__ Va,
    const unsigned short* __restrict__ Wq, const unsigned short* __restrict__ Wk,
    const unsigned short* __restrict__ Wv,
    const float* __restrict__ bqp, const float* __restrict__ bkp, const float* __restrict__ bvp,
    const float2* __restrict__ trig,
    unsigned short* __restrict__ Qb, unsigned short* __restrict__ Kb,
    unsigned short* __restrict__ Qr, unsigned short* __restrict__ Kr,
    unsigned short* __restrict__ Vt) {
  __shared__ unsigned short Al[128 * 64];
  __shared__ unsigned short Bl[128 * 64];
  const int tid = threadIdx.x;
  const int wave = tid >> 6, lane = tid & 63, g = lane >> 4, li = lane & 15;
  const int mbase = blockIdx.x * 128, nbase = blockIdx.y * 128;
  const int wm = wave >> 1, wn = wave & 1;
  const int which = blockIdx.z;
  const unsigned short* A = (which == 0) ? Qa : (which == 1) ? Ka : Va;
  const unsigned short* Wt = (which == 0) ? Wq : (which == 1) ? Wk : Wv;
  const float* bias = (which == 0) ? bqp : (which == 1) ? bkp : bvp;

  f32x4 acc[4][4];
#pragma unroll
  for (int i = 0; i < 4; ++i)
#pragma unroll
    for (int j = 0; j < 4; ++j) acc[i][j] = Z4;

  float bv4[4];
#pragma unroll
  for (int nt = 0; nt < 4; ++nt) bv4[nt] = bias[nbase + wn * 64 + nt * 16 + li];

  const int lr8 = lane >> 3, lc = lane & 7;
  const int xc8 = (lc ^ lr8) * 8;
  const unsigned short* srcA = A + (size_t)(mbase + wave * 32 + lr8) * Dn + xc8;
  const unsigned short* srcB = Wt + (size_t)(nbase + wave * 32 + lr8) * Dn + xc8;

  for (int kb = 0; kb < Dn; kb += 64) {
    __syncthreads();
#pragma unroll
    for (int i = 0; i < 4; ++i) {
      gll16(srcA + kb + (size_t)i * (8 * Dn), &Al[(wave * 32 + i * 8) * 64]);
      gll16(srcB + kb + (size_t)i * (8 * Dn), &Bl[(wave * 32 + i * 8) * 64]);
    }
    __syncthreads();
#pragma unroll
    for (int kc = 0; kc < 2; ++kc) {
      bf16x8 af[4], bfr[4];
#pragma unroll
      for (int mt = 0; mt < 4; ++mt) af[mt] = FR(Al, wm * 64 + mt * 16 + li, kc * 4 + g);
#pragma unroll
      for (int nt = 0; nt < 4; ++nt) bfr[nt] = FR(Bl, wn * 64 + nt * 16 + li, kc * 4 + g);
#pragma unroll
      for (int mt = 0; mt < 4; ++mt)
#pragma unroll
        for (int nt = 0; nt < 4; ++nt)
          acc[mt][nt] = MFMA(af[mt], bfr[nt], acc[mt][nt]);
    }
  }

  if (which < 2) {
    unsigned short* Ob = (which == 0) ? Qb : Kb;
    unsigned short* Or = (which == 0) ? Qr : Kr;
    const float presc = (which == 0) ? PRESC : 1.f;
#pragma unroll
    for (int mt = 0; mt < 4; ++mt) {
#pragma unroll
      for (int nt = 0; nt < 4; ++nt) {
        const int n = nbase + wn * 64 + nt * 16 + li;
        const int h = n >> 6, hd = n & 63;
        const int ti = hd >> 1;
        const float sgn = (hd & 1) ? 1.f : -1.f;
#pragma unroll
        for (int r = 0; r < 4; ++r) {
          const int m = mbase + wm * 64 + mt * 16 + 4 * g + r;
          const int b = m >> 11, s = m & (Sn - 1);
          const float v = (acc[mt][nt][r] + bv4[nt]) * presc;
          const size_t oi = (((size_t)(b * Hn + h)) * Sn + s) * HDn + hd;
          Ob[oi] = f2bf(v);
          const float p = __shfl_xor(v, 1);
          const float2 cs = trig[(s << 5) + ti];
          Or[oi] = f2bf(fmaf(sgn * p, cs.y, v * cs.x));
        }
      }
    }
  } else {
#pragma unroll
    for (int mt = 0; mt < 4; ++mt) {
#pragma unroll
      for (int nt = 0; nt < 4; ++nt) {
        const int n = nbase + wn * 64 + nt * 16 + li;
        const int h = n >> 6, hd = n & 63;
        const int m0 = mbase + wm * 64 + mt * 16 + 4 * g;
        const int b = m0 >> 11, s0 = m0 & (Sn - 1);
        u16x4 pk;
#pragma unroll
        for (int r = 0; r < 4; ++r) pk[r] = f2bf(acc[mt][nt][r] + bv4[nt]);
        *(u16x4*)&Vt[(((size_t)(b * Hn + h)) * HDn + hd) * Sn + s0] = pk;
      }
    }
  }
}

// ---------------------------------------------------------------------------
// 2. Output GEMM 64x128 tile (gll-staged): A bf16 [4096][1024], out f32 + bias
// ---------------------------------------------------------------------------
__global__ __launch_bounds__(256) void k_gemm_out(const unsigned short* __restrict__ A,
                                                  const unsigned short* __restrict__ Wt,
                                                  const float* __restrict__ bias,
                                                  float* __restrict__ out) {
  __shared__ unsigned short Al[64 * 64];
  __shared__ unsigned short Bl[128 * 64];
  const int tid = threadIdx.x;
  const int wave = tid >> 6, lane = tid & 63, g = lane >> 4, li = lane & 15;
  const int mbase = blockIdx.x * 64, nbase = blockIdx.y * 128;
  const int wm = wave >> 1, wn = wave & 1;

  f32x4 acc[2][4];
#pragma unroll
  for (int i = 0; i < 2; ++i)
#pragma unroll
    for (int j = 0; j < 4; ++j) acc[i][j] = Z4;

  float bv4[4];
#pragma unroll
  for (int nt = 0; nt < 4; ++nt) bv4[nt] = bias[nbase + wn * 64 + nt * 16 + li];

  const int lr8 = lane >> 3, lc = lane & 7;
  const int xc8 = (lc ^ lr8) * 8;
  const unsigned short* srcA = A + (size_t)(mbase + wave * 16 + lr8) * Dn + xc8;
  const unsigned short* srcB = Wt + (size_t)(nbase + wave * 32 + lr8) * Dn + xc8;

  for (int kb = 0; kb < Dn; kb += 64) {
    __syncthreads();
#pragma unroll
    for (int i = 0; i < 2; ++i)
      gll16(srcA + kb + (size_t)i * (8 * Dn), &Al[(wave * 16 + i * 8) * 64]);
#pragma unroll
    for (int i = 0; i < 4; ++i)
      gll16(srcB + kb + (size_t)i * (8 * Dn), &Bl[(wave * 32 + i * 8) * 64]);
    __syncthreads();
#pragma unroll
    for (int kc = 0; kc < 2; ++kc) {
      bf16x8 af[2], bfr[4];
#pragma unroll
      for (int mt = 0; mt < 2; ++mt) af[mt] = FR(Al, wm * 32 + mt * 16 + li, kc * 4 + g);
#pragma unroll
      for (int nt = 0; nt < 4; ++nt) bfr[nt] = FR(Bl, wn * 64 + nt * 16 + li, kc * 4 + g);
#pragma unroll
      for (int mt = 0; mt < 2; ++mt)
#pragma unroll
        for (int nt = 0; nt < 4; ++nt)
          acc[mt][nt] = MFMA(af[mt], bfr[nt], acc[mt][nt]);
    }
  }

#pragma unroll
  for (int mt = 0; mt < 2; ++mt)
#pragma unroll
    for (int nt = 0; nt < 4; ++nt) {
      const int n = nbase + wn * 64 + nt * 16 + li;
#pragma unroll
      for (int r = 0; r < 4; ++r) {
        const int m = mbase + wm * 32 + mt * 16 + 4 * g + r;
        out[(size_t)m * Dn + n] = acc[mt][nt][r] + bv4[nt];
      }
    }
}

// ---------------------------------------------------------------------------
// 3. Attention (round-9 structure; may_alias P-store fix; stride-256 map).
//    grid 1024 blocks, 4 waves x 16 q-rows each. Swapped QK^T, exp2 algebra,
//    no max tracking. LDS 40 KB -> 4 blocks/CU, 4 waves/SIMD.
// ---------------------------------------------------------------------------
__global__ __launch_bounds__(256, 4) void k_attn(
    const unsigned short* __restrict__ Qr, const unsigned short* __restrict__ Kr,
    const unsigned short* __restrict__ Qb, const unsigned short* __restrict__ Kb,
    const unsigned short* __restrict__ Vt, unsigned short* __restrict__ Zb) {
  __shared__ unsigned short KT[2][8192];  // 32 KB: passA = 128x64 Kb; passB = [Kr 64x64 | Vt 64x64]
  __shared__ unsigned short Pl[4][1024];  // 8 KB per-wave P [q][k] swizzled

  const int tid = threadIdx.x;
  const int wave = tid >> 6, lane = tid & 63, g = lane >> 4, li = lane & 15;
  // stride-256-balanced bijective map (see header comment)
  const int bid = blockIdx.x;
  const int x = bid & 7, m = bid >> 3;
  const int Qd = m >> 5, wv = m & 31, v = wv & 7;
  const int bh = x * 4 + (wv >> 3);
  const int qt = (Qd == 0) ? v : (Qd == 1) ? 15 - v : (Qd == 2) ? 16 + v : 31 - v;
  const int qw = qt * 64 + wave * 16;
  const size_t kvbase = (size_t)bh * (Sn * HDn);

  // Q fragments (prescaled by PRESC at projection)
  bf16x8 qrf[2], qbf[2];
#pragma unroll
  for (int kc = 0; kc < 2; ++kc) {
    const size_t a = kvbase + (size_t)(qw + li) * HDn + kc * 32 + g * 8;
    qrf[kc] = *(const bf16x8*)(Qr + a);
    qbf[kc] = *(const bf16x8*)(Qb + a);
  }

  const int lr8 = lane >> 3, lc = lane & 7;
  const int xc8 = (lc ^ lr8) * 8;  // source-side swizzle

  // pass A: whole block stages one 128x64 Kb tile; wave covers rows wave*32..+31
  const unsigned short* srcPA = Kb + kvbase + (size_t)(wave * 32 + lr8) * HDn + xc8;
  // pass B: tw = tensor (0=Kr rows k, 1=Vt rows hd), rbB = row base
  const int tw = wave >> 1, rbB = (wave & 1) * 32;
  const unsigned short* srcKrB = Kr + kvbase + (size_t)(rbB + lr8) * HDn + xc8;
  const unsigned short* srcVtB = Vt + kvbase + (size_t)(rbB + lr8) * Sn + xc8;
  const size_t strIB = tw ? (size_t)(8 * Sn) : (size_t)(8 * HDn);
  unsigned short* myP = &Pl[wave][0];

  // diag masks: k-offset 4g+r causal-valid vs q-offset li (tile-invariant)
  bool dm[4];
#pragma unroll
  for (int r = 0; r < 4; ++r) dm[r] = (4 * g + r) <= li;

#define STAGE_PA(kb_, buf_)                                 \
  do {                                                      \
    unsigned short* d_ = &KT[buf_][(wave * 32) * 64];       \
    const unsigned short* s_ = srcPA + (size_t)(kb_)*HDn;   \
    gll16(s_, d_);                                          \
    gll16(s_ + 8 * HDn, d_ + 8 * 64);                       \
    gll16(s_ + 16 * HDn, d_ + 16 * 64);                     \
    gll16(s_ + 24 * HDn, d_ + 24 * 64);                     \
  } while (0)

#define STAGE_B(kb_, buf_)                                                    \
  do {                                                                        \
    unsigned short* d_ = &KT[buf_][tw * 4096 + rbB * 64];                     \
    const unsigned short* s_ =                                                \
        tw ? (srcVtB + (size_t)(kb_)) : (srcKrB + (size_t)(kb_)*HDn);         \
    gll16(s_, d_);                                                            \
    gll16(s_ + strIB, d_ + 8 * 64);                                           \
    gll16(s_ + 2 * strIB, d_ + 16 * 64);                                      \
    gll16(s_ + 3 * strIB, d_ + 24 * 64);                                      \
  } while (0)

  // ------------------- PASS A: den = sum over ALL k of 2^(s') -------------------
  float d4[4] = {0.f, 0.f, 0.f, 0.f};
  STAGE_PA(0, 0);
  __syncthreads();
  for (int t = 0; t < Sn / 128; ++t) {
    if (t + 1 < Sn / 128) STAGE_PA((t + 1) * 128, (t + 1) & 1);
    const unsigned short* TK = &KT[t & 1][0];
#pragma unroll
    for (int nt = 0; nt < 8; ++nt) {
      const int krow = nt * 16 + li;
      const bf16x8 kf0 = FR(TK, krow, g), kf1 = FR(TK, krow, 4 + g);
      f32x4 s = Z4;
      s = MFMA(kf0, qbf[0], s);
      s = MFMA(kf1, qbf[1], s);
#pragma unroll
      for (int r = 0; r < 4; ++r) d4[r] += EXP2(s[r]);
    }
    __syncthreads();
  }
  float den = (d4[0] + d4[1]) + (d4[2] + d4[3]);
  den += __shfl_xor(den, 16);
  den += __shfl_xor(den, 32);
  const float Lc = LOG2(den) - C2;  // lane's q = qw+li; A = 2^(s' - Lc)
  const f32x4 mLc = {-Lc, -Lc, -Lc, -Lc};

  // ------------------- PASS B: w = 2^A (no max; A bounded), Z = P.V -------------
  f32x4 accz[4];
#pragma unroll
  for (int i = 0; i < 4; ++i) accz[i] = Z4;
  float ws[4] = {0.f, 0.f, 0.f, 0.f};
  const int NTB = qt + 1;

  STAGE_B(0, 0);
  __syncthreads();
  for (int t = 0; t < NTB; ++t) {
    if (t + 1 < NTB) STAGE_B((t + 1) * 64, (t + 1) & 1);
    const unsigned short* T0 = &KT[t & 1][0];         // Kr [k][hd]
    const unsigned short* TV = &KT[t & 1][0] + 4096;  // Vt [hd][k]
    const bool last = (t == qt);
#pragma unroll
    for (int nt = 0; nt < 4; ++nt) {
      float w4[4];
      if (!last || nt <= wave) {
        const int krow = nt * 16 + li;
        const bf16x8 kf0 = FR(T0, krow, g), kf1 = FR(T0, krow, 4 + g);
        f32x4 s = mLc;
        s = MFMA(kf0, qrf[0], s);
        s = MFMA(kf1, qrf[1], s);
        if (last && nt == wave) {  // diagonal subtile
#pragma unroll
          for (int r = 0; r < 4; ++r) {
            const float e = EXP2(EXP2(s[r]));
            w4[r] = dm[r] ? e : 0.f;
            ws[r] += w4[r];
          }
        } else {
#pragma unroll
          for (int r = 0; r < 4; ++r) {
            w4[r] = EXP2(EXP2(s[r]));
            ws[r] += w4[r];
          }
        }
      } else {
        w4[0] = w4[1] = w4[2] = w4[3] = 0.f;
      }
      const int adr = li * 64 + (((nt * 2 + (g >> 1)) ^ (li & 7)) * 8) + (g & 1) * 4;
      // may_alias store: must not be reordered against the FR() reads below
      *(uint2a*)&myP[adr] = (uint2a){cvtpk(w4[0], w4[1]), cvtpk(w4[2], w4[3])};
    }
    // hard fence: no instruction (esp. the PV ds_reads) may cross above here
    __builtin_amdgcn_sched_barrier(0);
    // PV: accz[n2] = Z[q = qw+4g+r][hd = n2*16+li]
#pragma unroll
    for (int kc = 0; kc < 2; ++kc) {
      const bf16x8 pa = FR(myP, li, kc * 4 + g);
#pragma unroll
      for (int n2 = 0; n2 < 4; ++n2) {
        const bf16x8 vb = FR(TV, n2 * 16 + li, kc * 4 + g);
        accz[n2] = MFMA(pa, vb, accz[n2]);
      }
    }
    __syncthreads();
  }

  // normalize + write bf16 [b*S+q][H*HD]
  float wsum = (ws[0] + ws[1]) + (ws[2] + ws[3]);
  wsum += __shfl_xor(wsum, 16);
  wsum += __shfl_xor(wsum, 32);  // lane holds wsum for q = qw+li
  float rw[4];
#pragma unroll
  for (int r = 0; r < 4; ++r) rw[r] = 1.f / __shfl(wsum, 4 * g + r);
  const int b = bh >> 4, h = bh & 15;
#pragma unroll
  for (int n2 = 0; n2 < 4; ++n2) {
#pragma unroll
    for (int r = 0; r < 4; ++r) {
      const int hd = n2 * 16 + li;
      const int q = qw + 4 * g + r;
      Zb[((size_t)(b * Sn + q)) * Dn + h * HDn + hd] = f2bf(accz[n2][r] * rw[r]);
    }
  }
#undef STAGE_PA
#undef STAGE_B
}

// ---------------------------------------------------------------------------
extern "C" void kernel_launch(void* const* d_in, const int* in_sizes, int n_in,
                              void* d_out, int out_size, void* d_ws, size_t ws_size,
                              hipStream_t stream) {
  const float* query = (const float*)d_in[0];
  const float* key   = (const float*)d_in[1];
  const float* value = (const float*)d_in[2];
  const float* Wq = (const float*)d_in[4];
  const float* bq = (const float*)d_in[5];
  const float* Wk = (const float*)d_in[6];
  const float* bk = (const float*)d_in[7];
  const float* Wv = (const float*)d_in[8];
  const float* bv = (const float*)d_in[9];
  const float* Wo = (const float*)d_in[10];
  const float* bo = (const float*)d_in[11];

  char* ws = (char*)d_ws;
  const size_t MB = 1ull << 20;
  unsigned short* Wqt = (unsigned short*)(ws + 0 * MB);
  unsigned short* Wkt = (unsigned short*)(ws + 2 * MB);
  unsigned short* Wvt = (unsigned short*)(ws + 4 * MB);
  unsigned short* Wot = (unsigned short*)(ws + 6 * MB);
  float2* trig        = (float2*)(ws + 8 * MB);           // 512 KB
  unsigned short* Qa  = (unsigned short*)(ws + 9 * MB);   // bf16 activations
  unsigned short* Ka  = (unsigned short*)(ws + 17 * MB);
  unsigned short* Va  = (unsigned short*)(ws + 25 * MB);
  unsigned short* Qb  = (unsigned short*)(ws + 33 * MB);  // [b,h,s,hd] (Q prescaled)
  unsigned short* Kb  = (unsigned short*)(ws + 41 * MB);
  unsigned short* Qr  = (unsigned short*)(ws + 49 * MB);
  unsigned short* Kr  = (unsigned short*)(ws + 57 * MB);
  unsigned short* Vt  = (unsigned short*)(ws + 65 * MB);  // [b,h,hd,s]
  unsigned short* Zb  = (unsigned short*)(ws + 73 * MB);  // [m][1024] bf16

  k_pre<<<7424, 256, 0, stream>>>(Wq, Wk, Wv, Wo, Wqt, Wkt, Wvt, Wot,
                                  query, key, value, Qa, Ka, Va, trig);
  k_gemm_proj<<<dim3(32, 8, 3), 256, 0, stream>>>(Qa, Ka, Va, Wqt, Wkt, Wvt,
                                                  bq, bk, bv, trig, Qb, Kb, Qr, Kr, Vt);
  k_attn<<<1024, 256, 0, stream>>>(Qr, Kr, Qb, Kb, Vt, Zb);
  k_gemm_out<<<dim3(64, 8), 256, 0, stream>>>(Zb, Wot, bo, (float*)d_out);
}

// Round 12
// 135.419 us; speedup vs baseline: 1.3678x; 1.0100x over previous
//
#include <hip/hip_runtime.h>

// ---------------------------------------------------------------------------
// RoPE Multi-Headed Attention (quirky softmax(exp(qr·kr)/den) variant)
// B=2, S=2048, D=1024, H=16, HD=64
// Round 12 = round 11 (green, 136.8us) + ONE delta: k_gemm_proj epilogue
// rewritten as LDS-bounce + fully-coalesced u16x8 stores (was: 128 scattered
// 2B stores + 64 shfl + strided trig loads per thread). Barrier-protected
// (no TBAA exposure). V path and all other kernels byte-identical.
// ---------------------------------------------------------------------------

#define Bn 2
#define Sn 2048
#define Dn 1024
#define Hn 16
#define HDn 64

typedef __attribute__((ext_vector_type(8))) short bf16x8;
typedef __attribute__((ext_vector_type(8))) unsigned short u16x8;
typedef __attribute__((ext_vector_type(4))) unsigned short u16x4;
typedef __attribute__((ext_vector_type(4))) float f32x4;
typedef uint2 __attribute__((may_alias)) uint2a;  // aliases everything: orders LDS P-store vs reads

#define MFMA(a, b, c) __builtin_amdgcn_mfma_f32_16x16x32_bf16(a, b, c, 0, 0, 0)
#define Z4 ((f32x4){0.f, 0.f, 0.f, 0.f})

// 0.125 * log2(e): folds the 1/sqrt(HD) scale and the exp->exp2 change into Q
#define PRESC 0.18033688011112042f
// log2(log2(e)): A = a*log2(e) = 2^(s' - L2 + C2)
#define C2 0.5287663729448977f

#define EXP2(x) __builtin_amdgcn_exp2f(x)
#define LOG2(x) __builtin_amdgcn_logf(x)

__device__ __forceinline__ unsigned short f2bf(float f) {
  unsigned int u = __builtin_bit_cast(unsigned int, f);
  u = (u + 0x7fffu + ((u >> 16) & 1u)) >> 16;
  return (unsigned short)u;
}
__device__ __forceinline__ float bf2f(unsigned short u) {
  return __builtin_bit_cast(float, (unsigned int)u << 16);
}

__device__ __forceinline__ unsigned int cvtpk(float lo, float hi) {
  unsigned int r;
  asm("v_cvt_pk_bf16_f32 %0, %1, %2" : "=v"(r) : "v"(lo), "v"(hi));
  return r;
}

// async global->LDS, 16B per lane; dst is wave-uniform base (lane writes +lane*16B)
__device__ __forceinline__ void gll16(const unsigned short* g, unsigned short* l) {
  __builtin_amdgcn_global_load_lds((const __attribute__((address_space(1))) void*)g,
                                   (__attribute__((address_space(3))) void*)l, 16, 0, 0);
}

// swizzled fragment read: LDS slot c of row r holds source chunk c^(r&7)
#define FR(T, row, x) (*(const bf16x8*)&(T)[(row) * 64 + (((x) ^ ((row) & 7)) * 8)])

// ---------------------------------------------------------------------------
// 0. k_pre: merged trig table + weight transpose + activation convert.
//    blocks [0,256): trig; [256,1280): wtrans; [1280,7424): cvt
// ---------------------------------------------------------------------------
__global__ __launch_bounds__(256) void k_pre(
    const float* __restrict__ W0, const float* __restrict__ W1,
    const float* __restrict__ W2, const float* __restrict__ W3,
    unsigned short* __restrict__ O0, unsigned short* __restrict__ O1,
    unsigned short* __restrict__ O2, unsigned short* __restrict__ O3,
    const float* __restrict__ qa, const float* __restrict__ ka, const float* __restrict__ va,
    unsigned short* __restrict__ oq, unsigned short* __restrict__ ok,
    unsigned short* __restrict__ ov, float2* __restrict__ T) {
  __shared__ float t[64][65];
  const int b = blockIdx.x;
  const int tid = threadIdx.x;
  if (b < 256) {
    const int idx = b * 256 + tid;  // 65536
    const int s = idx >> 5, i = idx & 31;
    const float theta = powf(1000.f, -(float)i / 32.f);
    const float pm = (float)s * theta;
    T[idx] = make_float2(cosf(pm), sinf(pm));
  } else if (b < 1280) {
    const int w = b - 256;
    const int which = w >> 8, rem = w & 255;
    const float* W = (which == 0) ? W0 : (which == 1) ? W1 : (which == 2) ? W2 : W3;
    unsigned short* O = (which == 0) ? O0 : (which == 1) ? O1 : (which == 2) ? O2 : O3;
    const int kb = (rem >> 4) * 64, nb = (rem & 15) * 64;
#pragma unroll
    for (int rep = 0; rep < 16; ++rep) {
      const int e = rep * 256 + tid;
      const int k = e >> 6, n = e & 63;
      t[k][n] = W[(kb + k) * Dn + nb + n];
    }
    __syncthreads();
#pragma unroll
    for (int rep = 0; rep < 16; ++rep) {
      const int e = rep * 256 + tid;
      const int n = e >> 6, k = e & 63;
      O[(nb + n) * Dn + kb + k] = f2bf(t[k][n]);
    }
  } else {
    const int c = b - 1280;  // 6144 blocks
    const int z = c >> 11, cx = c & 2047;
    const float* s = (z == 0) ? qa : (z == 1) ? ka : va;
    unsigned short* d = (z == 0) ? oq : (z == 1) ? ok : ov;
    const size_t idx = ((size_t)cx * 256 + tid) * 8;
    float4 a0 = *(const float4*)(s + idx);
    float4 b0 = *(const float4*)(s + idx + 4);
    u16x8 pk;
    pk[0] = f2bf(a0.x); pk[1] = f2bf(a0.y); pk[2] = f2bf(a0.z); pk[3] = f2bf(a0.w);
    pk[4] = f2bf(b0.x); pk[5] = f2bf(b0.y); pk[6] = f2bf(b0.z); pk[7] = f2bf(b0.w);
    *(u16x8*)(d + idx) = pk;
  }
}

// ---------------------------------------------------------------------------
// 1. Fused QKV projection GEMM (gll-staged). grid (32, 8, 3); z = {Q,K,V}.
//    Q: prescaled by PRESC; Q/K write base + roped via LDS-bounce coalesced
//    epilogue; V writes Vt [b,h,hd,s].
// ---------------------------------------------------------------------------
__global__ __launch_bounds__(256) void k_gemm_proj(
    const unsigned short* __restrict__ Qa, const unsigned short* __restrict__ Ka,
    const unsigned short* __restrict__ Va,
    const unsigned short* __restrict__ Wq, const unsigned short* __restrict__ Wk,
    const unsigned short* __restrict__ Wv,
    const float* __restrict__ bqp, const float* __restrict__ bkp, const float* __restrict__ bvp,
    const float2* __restrict__ trig,
    unsigned short* __restrict__ Qb, unsigned short* __restrict__ Kb,
    unsigned short* __restrict__ Qr, unsigned short* __restrict__ Kr,
    unsigned short* __restrict__ Vt) {
  // staging: Al = SH[0..8192), Bl = SH[8192..16384); epilogue: [128][136] tile
  __shared__ unsigned short SH[17408];  // 34.8 KB
  unsigned short* Al = SH;
  unsigned short* Bl = SH + 8192;
  const int tid = threadIdx.x;
  const int wave = tid >> 6, lane = tid & 63, g = lane >> 4, li = lane & 15;
  const int mbase = blockIdx.x * 128, nbase = blockIdx.y * 128;
  const int wm = wave >> 1, wn = wave & 1;
  const int which = blockIdx.z;
  const unsigned short* A = (which == 0) ? Qa : (which == 1) ? Ka : Va;
  const unsigned short* Wt = (which == 0) ? Wq : (which == 1) ? Wk : Wv;
  const float* bias = (which == 0) ? bqp : (which == 1) ? bkp : bvp;

  f32x4 acc[4][4];
#pragma unroll
  for (int i = 0; i < 4; ++i)
#pragma unroll
    for (int j = 0; j < 4; ++j) acc[i][j] = Z4;

  float bv4[4];
#pragma unroll
  for (int nt = 0; nt < 4; ++nt) bv4[nt] = bias[nbase + wn * 64 + nt * 16 + li];

  const int lr8 = lane >> 3, lc = lane & 7;
  const int xc8 = (lc ^ lr8) * 8;
  const unsigned short* srcA = A + (size_t)(mbase + wave * 32 + lr8) * Dn + xc8;
  const unsigned short* srcB = Wt + (size_t)(nbase + wave * 32 + lr8) * Dn + xc8;

  for (int kb = 0; kb < Dn; kb += 64) {
    __syncthreads();
#pragma unroll
    for (int i = 0; i < 4; ++i) {
      gll16(srcA + kb + (size_t)i * (8 * Dn), &Al[(wave * 32 + i * 8) * 64]);
      gll16(srcB + kb + (size_t)i * (8 * Dn), &Bl[(wave * 32 + i * 8) * 64]);
    }
    __syncthreads();
#pragma unroll
    for (int kc = 0; kc < 2; ++kc) {
      bf16x8 af[4], bfr[4];
#pragma unroll
      for (int mt = 0; mt < 4; ++mt) af[mt] = FR(Al, wm * 64 + mt * 16 + li, kc * 4 + g);
#pragma unroll
      for (int nt = 0; nt < 4; ++nt) bfr[nt] = FR(Bl, wn * 64 + nt * 16 + li, kc * 4 + g);
#pragma unroll
      for (int mt = 0; mt < 4; ++mt)
#pragma unroll
        for (int nt = 0; nt < 4; ++nt)
          acc[mt][nt] = MFMA(af[mt], bfr[nt], acc[mt][nt]);
    }
  }

  if (which < 2) {
    unsigned short* Ob = (which == 0) ? Qb : Kb;
    unsigned short* Or = (which == 0) ? Qr : Kr;
    const float presc = (which == 0) ? PRESC : 1.f;
    __syncthreads();  // all waves done reading Al/Bl staging
    // write phase: bf16 tile [128 m][136-padded n]
#pragma unroll
    for (int mt = 0; mt < 4; ++mt)
#pragma unroll
      for (int nt = 0; nt < 4; ++nt) {
        const int nl = wn * 64 + nt * 16 + li;
#pragma unroll
        for (int r = 0; r < 4; ++r) {
          const int ml = wm * 64 + mt * 16 + 4 * g + r;
          SH[ml * 136 + nl] = f2bf((acc[mt][nt][r] + bv4[nt]) * presc);
        }
      }
    __syncthreads();
    // read phase: 8-lane groups cover one 64-col half-row -> coalesced stores
#pragma unroll
    for (int hp = 0; hp < 2; ++hp) {
#pragma unroll
      for (int pass = 0; pass < 4; ++pass) {
        const int row = pass * 32 + wave * 8 + (lane >> 3);
        const int nl = hp * 64 + (lane & 7) * 8;
        const int mg = mbase + row;
        const int bi = mg >> 11, sg = mg & (Sn - 1);
        const int ng = nbase + nl;
        const int h = ng >> 6, hd = ng & 63;
        const u16x8 v = *(const u16x8*)&SH[row * 136 + nl];
        u16x8 o;
        const float2* tp = trig + (sg << 5) + (hd >> 1);
#pragma unroll
        for (int j = 0; j < 4; ++j) {
          const float x0 = bf2f(v[2 * j]), x1 = bf2f(v[2 * j + 1]);
          const float2 cs = tp[j];
          o[2 * j] = f2bf(x0 * cs.x - x1 * cs.y);
          o[2 * j + 1] = f2bf(x1 * cs.x + x0 * cs.y);
        }
        const size_t oi = (((size_t)(bi * Hn + h)) * Sn + sg) * HDn + hd;
        *(u16x8*)(Ob + oi) = v;
        *(u16x8*)(Or + oi) = o;
      }
    }
  } else {
#pragma unroll
    for (int mt = 0; mt < 4; ++mt) {
#pragma unroll
      for (int nt = 0; nt < 4; ++nt) {
        const int n = nbase + wn * 64 + nt * 16 + li;
        const int h = n >> 6, hd = n & 63;
        const int m0 = mbase + wm * 64 + mt * 16 + 4 * g;
        const int b = m0 >> 11, s0 = m0 & (Sn - 1);
        u16x4 pk;
#pragma unroll
        for (int r = 0; r < 4; ++r) pk[r] = f2bf(acc[mt][nt][r] + bv4[nt]);
        *(u16x4*)&Vt[(((size_t)(b * Hn + h)) * HDn + hd) * Sn + s0] = pk;
      }
    }
  }
}

// ---------------------------------------------------------------------------
// 2. Output GEMM 64x128 tile (gll-staged): A bf16 [4096][1024], out f32 + bias
// ---------------------------------------------------------------------------
__global__ __launch_bounds__(256) void k_gemm_out(const unsigned short* __restrict__ A,
                                                  const unsigned short* __restrict__ Wt,
                                                  const float* __restrict__ bias,
                                                  float* __restrict__ out) {
  __shared__ unsigned short Al[64 * 64];
  __shared__ unsigned short Bl[128 * 64];
  const int tid = threadIdx.x;
  const int wave = tid >> 6, lane = tid & 63, g = lane >> 4, li = lane & 15;
  const int mbase = blockIdx.x * 64, nbase = blockIdx.y * 128;
  const int wm = wave >> 1, wn = wave & 1;

  f32x4 acc[2][4];
#pragma unroll
  for (int i = 0; i < 2; ++i)
#pragma unroll
    for (int j = 0; j < 4; ++j) acc[i][j] = Z4;

  float bv4[4];
#pragma unroll
  for (int nt = 0; nt < 4; ++nt) bv4[nt] = bias[nbase + wn * 64 + nt * 16 + li];

  const int lr8 = lane >> 3, lc = lane & 7;
  const int xc8 = (lc ^ lr8) * 8;
  const unsigned short* srcA = A + (size_t)(mbase + wave * 16 + lr8) * Dn + xc8;
  const unsigned short* srcB = Wt + (size_t)(nbase + wave * 32 + lr8) * Dn + xc8;

  for (int kb = 0; kb < Dn; kb += 64) {
    __syncthreads();
#pragma unroll
    for (int i = 0; i < 2; ++i)
      gll16(srcA + kb + (size_t)i * (8 * Dn), &Al[(wave * 16 + i * 8) * 64]);
#pragma unroll
    for (int i = 0; i < 4; ++i)
      gll16(srcB + kb + (size_t)i * (8 * Dn), &Bl[(wave * 32 + i * 8) * 64]);
    __syncthreads();
#pragma unroll
    for (int kc = 0; kc < 2; ++kc) {
      bf16x8 af[2], bfr[4];
#pragma unroll
      for (int mt = 0; mt < 2; ++mt) af[mt] = FR(Al, wm * 32 + mt * 16 + li, kc * 4 + g);
#pragma unroll
      for (int nt = 0; nt < 4; ++nt) bfr[nt] = FR(Bl, wn * 64 + nt * 16 + li, kc * 4 + g);
#pragma unroll
      for (int mt = 0; mt < 2; ++mt)
#pragma unroll
        for (int nt = 0; nt < 4; ++nt)
          acc[mt][nt] = MFMA(af[mt], bfr[nt], acc[mt][nt]);
    }
  }

#pragma unroll
  for (int mt = 0; mt < 2; ++mt)
#pragma unroll
    for (int nt = 0; nt < 4; ++nt) {
      const int n = nbase + wn * 64 + nt * 16 + li;
#pragma unroll
      for (int r = 0; r < 4; ++r) {
        const int m = mbase + wm * 32 + mt * 16 + 4 * g + r;
        out[(size_t)m * Dn + n] = acc[mt][nt][r] + bv4[nt];
      }
    }
}

// ---------------------------------------------------------------------------
// 3. Attention (round-11 verbatim: may_alias P-store fix; stride-256 map).
//    grid 1024 blocks, 4 waves x 16 q-rows each. Swapped QK^T, exp2 algebra,
//    no max tracking. LDS 40 KB -> 4 blocks/CU, 4 waves/SIMD.
// ---------------------------------------------------------------------------
__global__ __launch_bounds__(256, 4) void k_attn(
    const unsigned short* __restrict__ Qr, const unsigned short* __restrict__ Kr,
    const unsigned short* __restrict__ Qb, const unsigned short* __restrict__ Kb,
    const unsigned short* __restrict__ Vt, unsigned short* __restrict__ Zb) {
  __shared__ unsigned short KT[2][8192];  // 32 KB: passA = 128x64 Kb; passB = [Kr 64x64 | Vt 64x64]
  __shared__ unsigned short Pl[4][1024];  // 8 KB per-wave P [q][k] swizzled

  const int tid = threadIdx.x;
  const int wave = tid >> 6, lane = tid & 63, g = lane >> 4, li = lane & 15;
  // stride-256-balanced bijective map (see round-11 header)
  const int bid = blockIdx.x;
  const int x = bid & 7, m = bid >> 3;
  const int Qd = m >> 5, wv = m & 31, v = wv & 7;
  const int bh = x * 4 + (wv >> 3);
  const int qt = (Qd == 0) ? v : (Qd == 1) ? 15 - v : (Qd == 2) ? 16 + v : 31 - v;
  const int qw = qt * 64 + wave * 16;
  const size_t kvbase = (size_t)bh * (Sn * HDn);

  // Q fragments (prescaled by PRESC at projection)
  bf16x8 qrf[2], qbf[2];
#pragma unroll
  for (int kc = 0; kc < 2; ++kc) {
    const size_t a = kvbase + (size_t)(qw + li) * HDn + kc * 32 + g * 8;
    qrf[kc] = *(const bf16x8*)(Qr + a);
    qbf[kc] = *(const bf16x8*)(Qb + a);
  }

  const int lr8 = lane >> 3, lc = lane & 7;
  const int xc8 = (lc ^ lr8) * 8;  // source-side swizzle

  // pass A: whole block stages one 128x64 Kb tile; wave covers rows wave*32..+31
  const unsigned short* srcPA = Kb + kvbase + (size_t)(wave * 32 + lr8) * HDn + xc8;
  // pass B: tw = tensor (0=Kr rows k, 1=Vt rows hd), rbB = row base
  const int tw = wave >> 1, rbB = (wave & 1) * 32;
  const unsigned short* srcKrB = Kr + kvbase + (size_t)(rbB + lr8) * HDn + xc8;
  const unsigned short* srcVtB = Vt + kvbase + (size_t)(rbB + lr8) * Sn + xc8;
  const size_t strIB = tw ? (size_t)(8 * Sn) : (size_t)(8 * HDn);
  unsigned short* myP = &Pl[wave][0];

  // diag masks: k-offset 4g+r causal-valid vs q-offset li (tile-invariant)
  bool dm[4];
#pragma unroll
  for (int r = 0; r < 4; ++r) dm[r] = (4 * g + r) <= li;

#define STAGE_PA(kb_, buf_)                                 \
  do {                                                      \
    unsigned short* d_ = &KT[buf_][(wave * 32) * 64];       \
    const unsigned short* s_ = srcPA + (size_t)(kb_)*HDn;   \
    gll16(s_, d_);                                          \
    gll16(s_ + 8 * HDn, d_ + 8 * 64);                       \
    gll16(s_ + 16 * HDn, d_ + 16 * 64);                     \
    gll16(s_ + 24 * HDn, d_ + 24 * 64);                     \
  } while (0)

#define STAGE_B(kb_, buf_)                                                    \
  do {                                                                        \
    unsigned short* d_ = &KT[buf_][tw * 4096 + rbB * 64];                     \
    const unsigned short* s_ =                                                \
        tw ? (srcVtB + (size_t)(kb_)) : (srcKrB + (size_t)(kb_)*HDn);         \
    gll16(s_, d_);                                                            \
    gll16(s_ + strIB, d_ + 8 * 64);                                           \
    gll16(s_ + 2 * strIB, d_ + 16 * 64);                                      \
    gll16(s_ + 3 * strIB, d_ + 24 * 64);                                      \
  } while (0)

  // ------------------- PASS A: den = sum over ALL k of 2^(s') -------------------
  float d4[4] = {0.f, 0.f, 0.f, 0.f};
  STAGE_PA(0, 0);
  __syncthreads();
  for (int t = 0; t < Sn / 128; ++t) {
    if (t + 1 < Sn / 128) STAGE_PA((t + 1) * 128, (t + 1) & 1);
    const unsigned short* TK = &KT[t & 1][0];
#pragma unroll
    for (int nt = 0; nt < 8; ++nt) {
      const int krow = nt * 16 + li;
      const bf16x8 kf0 = FR(TK, krow, g), kf1 = FR(TK, krow, 4 + g);
      f32x4 s = Z4;
      s = MFMA(kf0, qbf[0], s);
      s = MFMA(kf1, qbf[1], s);
#pragma unroll
      for (int r = 0; r < 4; ++r) d4[r] += EXP2(s[r]);
    }
    __syncthreads();
  }
  float den = (d4[0] + d4[1]) + (d4[2] + d4[3]);
  den += __shfl_xor(den, 16);
  den += __shfl_xor(den, 32);
  const float Lc = LOG2(den) - C2;  // lane's q = qw+li; A = 2^(s' - Lc)
  const f32x4 mLc = {-Lc, -Lc, -Lc, -Lc};

  // ------------------- PASS B: w = 2^A (no max; A bounded), Z = P.V -------------
  f32x4 accz[4];
#pragma unroll
  for (int i = 0; i < 4; ++i) accz[i] = Z4;
  float ws[4] = {0.f, 0.f, 0.f, 0.f};
  const int NTB = qt + 1;

  STAGE_B(0, 0);
  __syncthreads();
  for (int t = 0; t < NTB; ++t) {
    if (t + 1 < NTB) STAGE_B((t + 1) * 64, (t + 1) & 1);
    const unsigned short* T0 = &KT[t & 1][0];         // Kr [k][hd]
    const unsigned short* TV = &KT[t & 1][0] + 4096;  // Vt [hd][k]
    const bool last = (t == qt);
#pragma unroll
    for (int nt = 0; nt < 4; ++nt) {
      float w4[4];
      if (!last || nt <= wave) {
        const int krow = nt * 16 + li;
        const bf16x8 kf0 = FR(T0, krow, g), kf1 = FR(T0, krow, 4 + g);
        f32x4 s = mLc;
        s = MFMA(kf0, qrf[0], s);
        s = MFMA(kf1, qrf[1], s);
        if (last && nt == wave) {  // diagonal subtile
#pragma unroll
          for (int r = 0; r < 4; ++r) {
            const float e = EXP2(EXP2(s[r]));
            w4[r] = dm[r] ? e : 0.f;
            ws[r] += w4[r];
          }
        } else {
#pragma unroll
          for (int r = 0; r < 4; ++r) {
            w4[r] = EXP2(EXP2(s[r]));
            ws[r] += w4[r];
          }
        }
      } else {
        w4[0] = w4[1] = w4[2] = w4[3] = 0.f;
      }
      const int adr = li * 64 + (((nt * 2 + (g >> 1)) ^ (li & 7)) * 8) + (g & 1) * 4;
      // may_alias store: must not be reordered against the FR() reads below
      *(uint2a*)&myP[adr] = (uint2a){cvtpk(w4[0], w4[1]), cvtpk(w4[2], w4[3])};
    }
    // hard fence: no instruction (esp. the PV ds_reads) may cross above here
    __builtin_amdgcn_sched_barrier(0);
    // PV: accz[n2] = Z[q = qw+4g+r][hd = n2*16+li]
#pragma unroll
    for (int kc = 0; kc < 2; ++kc) {
      const bf16x8 pa = FR(myP, li, kc * 4 + g);
#pragma unroll
      for (int n2 = 0; n2 < 4; ++n2) {
        const bf16x8 vb = FR(TV, n2 * 16 + li, kc * 4 + g);
        accz[n2] = MFMA(pa, vb, accz[n2]);
      }
    }
    __syncthreads();
  }

  // normalize + write bf16 [b*S+q][H*HD]
  float wsum = (ws[0] + ws[1]) + (ws[2] + ws[3]);
  wsum += __shfl_xor(wsum, 16);
  wsum += __shfl_xor(wsum, 32);  // lane holds wsum for q = qw+li
  float rw[4];
#pragma unroll
  for (int r = 0; r < 4; ++r) rw[r] = 1.f / __shfl(wsum, 4 * g + r);
  const int b = bh >> 4, h = bh & 15;
#pragma unroll
  for (int n2 = 0; n2 < 4; ++n2) {
#pragma unroll
    for (int r = 0; r < 4; ++r) {
      const int hd = n2 * 16 + li;
      const int q = qw + 4 * g + r;
      Zb[((size_t)(b * Sn + q)) * Dn + h * HDn + hd] = f2bf(accz[n2][r] * rw[r]);
    }
  }
#undef STAGE_PA
#undef STAGE_B
}

// ---------------------------------------------------------------------------
extern "C" void kernel_launch(void* const* d_in, const int* in_sizes, int n_in,
                              void* d_out, int out_size, void* d_ws, size_t ws_size,
                              hipStream_t stream) {
  const float* query = (const float*)d_in[0];
  const float* key   = (const float*)d_in[1];
  const float* value = (const float*)d_in[2];
  const float* Wq = (const float*)d_in[4];
  const float* bq = (const float*)d_in[5];
  const float* Wk = (const float*)d_in[6];
  const float* bk = (const float*)d_in[7];
  const float* Wv = (const float*)d_in[8];
  const float* bv = (const float*)d_in[9];
  const float* Wo = (const float*)d_in[10];
  const float* bo = (const float*)d_in[11];

  char* ws = (char*)d_ws;
  const size_t MB = 1ull << 20;
  unsigned short* Wqt = (unsigned short*)(ws + 0 * MB);
  unsigned short* Wkt = (unsigned short*)(ws + 2 * MB);
  unsigned short* Wvt = (unsigned short*)(ws + 4 * MB);
  unsigned short* Wot = (unsigned short*)(ws + 6 * MB);
  float2* trig        = (float2*)(ws + 8 * MB);           // 512 KB
  unsigned short* Qa  = (unsigned short*)(ws + 9 * MB);   // bf16 activations
  unsigned short* Ka  = (unsigned short*)(ws + 17 * MB);
  unsigned short* Va  = (unsigned short*)(ws + 25 * MB);
  unsigned short* Qb  = (unsigned short*)(ws + 33 * MB);  // [b,h,s,hd] (Q prescaled)
  unsigned short* Kb  = (unsigned short*)(ws + 41 * MB);
  unsigned short* Qr  = (unsigned short*)(ws + 49 * MB);
  unsigned short* Kr  = (unsigned short*)(ws + 57 * MB);
  unsigned short* Vt  = (unsigned short*)(ws + 65 * MB);  // [b,h,hd,s]
  unsigned short* Zb  = (unsigned short*)(ws + 73 * MB);  // [m][1024] bf16

  k_pre<<<7424, 256, 0, stream>>>(Wq, Wk, Wv, Wo, Wqt, Wkt, Wvt, Wot,
                                  query, key, value, Qa, Ka, Va, trig);
  k_gemm_proj<<<dim3(32, 8, 3), 256, 0, stream>>>(Qa, Ka, Va, Wqt, Wkt, Wvt,
                                                  bq, bk, bv, trig, Qb, Kb, Qr, Kr, Vt);
  k_attn<<<1024, 256, 0, stream>>>(Qr, Kr, Qb, Kb, Vt, Zb);
  k_gemm_out<<<dim3(64, 8), 256, 0, stream>>>(Zb, Wot, bo, (float*)d_out);
}

// Round 13
// 134.933 us; speedup vs baseline: 1.3727x; 1.0036x over previous
//
#include <hip/hip_runtime.h>

// ---------------------------------------------------------------------------
// RoPE Multi-Headed Attention (quirky softmax(exp(qr·kr)/den) variant)
// B=2, S=2048, D=1024, H=16, HD=64
// Round 13 = round 12 (green, 135.4us) + ONE delta: k_attn pass A slab-
// decomposed (wave computes ALL 64 block q-rows vs ITS OWN 32-row k-slab:
// 4x fewer pass-A ds_reads). Cross-wave den combine via may_alias float LDS
// reduction (double-barrier-protected). This is r8's structure, whose failure
// is attributed to the P-store TBAA race fixed in r11 (fix retained here).
// ---------------------------------------------------------------------------

#define Bn 2
#define Sn 2048
#define Dn 1024
#define Hn 16
#define HDn 64

typedef __attribute__((ext_vector_type(8))) short bf16x8;
typedef __attribute__((ext_vector_type(8))) unsigned short u16x8;
typedef __attribute__((ext_vector_type(4))) unsigned short u16x4;
typedef __attribute__((ext_vector_type(4))) float f32x4;
typedef uint2 __attribute__((may_alias)) uint2a;  // orders LDS P-store vs bf16x8 reads
typedef float __attribute__((may_alias)) floata;  // alias-safe LDS float reduction

#define MFMA(a, b, c) __builtin_amdgcn_mfma_f32_16x16x32_bf16(a, b, c, 0, 0, 0)
#define Z4 ((f32x4){0.f, 0.f, 0.f, 0.f})

// 0.125 * log2(e): folds the 1/sqrt(HD) scale and the exp->exp2 change into Q
#define PRESC 0.18033688011112042f
// log2(log2(e)): A = a*log2(e) = 2^(s' - L2 + C2)
#define C2 0.5287663729448977f

#define EXP2(x) __builtin_amdgcn_exp2f(x)
#define LOG2(x) __builtin_amdgcn_logf(x)

__device__ __forceinline__ unsigned short f2bf(float f) {
  unsigned int u = __builtin_bit_cast(unsigned int, f);
  u = (u + 0x7fffu + ((u >> 16) & 1u)) >> 16;
  return (unsigned short)u;
}
__device__ __forceinline__ float bf2f(unsigned short u) {
  return __builtin_bit_cast(float, (unsigned int)u << 16);
}

__device__ __forceinline__ unsigned int cvtpk(float lo, float hi) {
  unsigned int r;
  asm("v_cvt_pk_bf16_f32 %0, %1, %2" : "=v"(r) : "v"(lo), "v"(hi));
  return r;
}

// async global->LDS, 16B per lane; dst is wave-uniform base (lane writes +lane*16B)
__device__ __forceinline__ void gll16(const unsigned short* g, unsigned short* l) {
  __builtin_amdgcn_global_load_lds((const __attribute__((address_space(1))) void*)g,
                                   (__attribute__((address_space(3))) void*)l, 16, 0, 0);
}

// swizzled fragment read: LDS slot c of row r holds source chunk c^(r&7)
#define FR(T, row, x) (*(const bf16x8*)&(T)[(row) * 64 + (((x) ^ ((row) & 7)) * 8)])

// ---------------------------------------------------------------------------
// 0. k_pre: merged trig table + weight transpose + activation convert.
//    blocks [0,256): trig; [256,1280): wtrans; [1280,7424): cvt
// ---------------------------------------------------------------------------
__global__ __launch_bounds__(256) void k_pre(
    const float* __restrict__ W0, const float* __restrict__ W1,
    const float* __restrict__ W2, const float* __restrict__ W3,
    unsigned short* __restrict__ O0, unsigned short* __restrict__ O1,
    unsigned short* __restrict__ O2, unsigned short* __restrict__ O3,
    const float* __restrict__ qa, const float* __restrict__ ka, const float* __restrict__ va,
    unsigned short* __restrict__ oq, unsigned short* __restrict__ ok,
    unsigned short* __restrict__ ov, float2* __restrict__ T) {
  __shared__ float t[64][65];
  const int b = blockIdx.x;
  const int tid = threadIdx.x;
  if (b < 256) {
    const int idx = b * 256 + tid;  // 65536
    const int s = idx >> 5, i = idx & 31;
    const float theta = powf(1000.f, -(float)i / 32.f);
    const float pm = (float)s * theta;
    T[idx] = make_float2(cosf(pm), sinf(pm));
  } else if (b < 1280) {
    const int w = b - 256;
    const int which = w >> 8, rem = w & 255;
    const float* W = (which == 0) ? W0 : (which == 1) ? W1 : (which == 2) ? W2 : W3;
    unsigned short* O = (which == 0) ? O0 : (which == 1) ? O1 : (which == 2) ? O2 : O3;
    const int kb = (rem >> 4) * 64, nb = (rem & 15) * 64;
#pragma unroll
    for (int rep = 0; rep < 16; ++rep) {
      const int e = rep * 256 + tid;
      const int k = e >> 6, n = e & 63;
      t[k][n] = W[(kb + k) * Dn + nb + n];
    }
    __syncthreads();
#pragma unroll
    for (int rep = 0; rep < 16; ++rep) {
      const int e = rep * 256 + tid;
      const int n = e >> 6, k = e & 63;
      O[(nb + n) * Dn + kb + k] = f2bf(t[k][n]);
    }
  } else {
    const int c = b - 1280;  // 6144 blocks
    const int z = c >> 11, cx = c & 2047;
    const float* s = (z == 0) ? qa : (z == 1) ? ka : va;
    unsigned short* d = (z == 0) ? oq : (z == 1) ? ok : ov;
    const size_t idx = ((size_t)cx * 256 + tid) * 8;
    float4 a0 = *(const float4*)(s + idx);
    float4 b0 = *(const float4*)(s + idx + 4);
    u16x8 pk;
    pk[0] = f2bf(a0.x); pk[1] = f2bf(a0.y); pk[2] = f2bf(a0.z); pk[3] = f2bf(a0.w);
    pk[4] = f2bf(b0.x); pk[5] = f2bf(b0.y); pk[6] = f2bf(b0.z); pk[7] = f2bf(b0.w);
    *(u16x8*)(d + idx) = pk;
  }
}

// ---------------------------------------------------------------------------
// 1. Fused QKV projection GEMM (gll-staged). grid (32, 8, 3); z = {Q,K,V}.
//    Q: prescaled by PRESC; Q/K write base + roped via LDS-bounce coalesced
//    epilogue; V writes Vt [b,h,hd,s].
// ---------------------------------------------------------------------------
__global__ __launch_bounds__(256) void k_gemm_proj(
    const unsigned short* __restrict__ Qa, const unsigned short* __restrict__ Ka,
    const unsigned short* __restrict__ Va,
    const unsigned short* __restrict__ Wq, const unsigned short* __restrict__ Wk,
    const unsigned short* __restrict__ Wv,
    const float* __restrict__ bqp, const float* __restrict__ bkp, const float* __restrict__ bvp,
    const float2* __restrict__ trig,
    unsigned short* __restrict__ Qb, unsigned short* __restrict__ Kb,
    unsigned short* __restrict__ Qr, unsigned short* __restrict__ Kr,
    unsigned short* __restrict__ Vt) {
  // staging: Al = SH[0..8192), Bl = SH[8192..16384); epilogue: [128][136] tile
  __shared__ unsigned short SH[17408];  // 34.8 KB
  unsigned short* Al = SH;
  unsigned short* Bl = SH + 8192;
  const int tid = threadIdx.x;
  const int wave = tid >> 6, lane = tid & 63, g = lane >> 4, li = lane & 15;
  const int mbase = blockIdx.x * 128, nbase = blockIdx.y * 128;
  const int wm = wave >> 1, wn = wave & 1;
  const int which = blockIdx.z;
  const unsigned short* A = (which == 0) ? Qa : (which == 1) ? Ka : Va;
  const unsigned short* Wt = (which == 0) ? Wq : (which == 1) ? Wk : Wv;
  const float* bias = (which == 0) ? bqp : (which == 1) ? bkp : bvp;

  f32x4 acc[4][4];
#pragma unroll
  for (int i = 0; i < 4; ++i)
#pragma unroll
    for (int j = 0; j < 4; ++j) acc[i][j] = Z4;

  float bv4[4];
#pragma unroll
  for (int nt = 0; nt < 4; ++nt) bv4[nt] = bias[nbase + wn * 64 + nt * 16 + li];

  const int lr8 = lane >> 3, lc = lane & 7;
  const int xc8 = (lc ^ lr8) * 8;
  const unsigned short* srcA = A + (size_t)(mbase + wave * 32 + lr8) * Dn + xc8;
  const unsigned short* srcB = Wt + (size_t)(nbase + wave * 32 + lr8) * Dn + xc8;

  for (int kb = 0; kb < Dn; kb += 64) {
    __syncthreads();
#pragma unroll
    for (int i = 0; i < 4; ++i) {
      gll16(srcA + kb + (size_t)i * (8 * Dn), &Al[(wave * 32 + i * 8) * 64]);
      gll16(srcB + kb + (size_t)i * (8 * Dn), &Bl[(wave * 32 + i * 8) * 64]);
    }
    __syncthreads();
#pragma unroll
    for (int kc = 0; kc < 2; ++kc) {
      bf16x8 af[4], bfr[4];
#pragma unroll
      for (int mt = 0; mt < 4; ++mt) af[mt] = FR(Al, wm * 64 + mt * 16 + li, kc * 4 + g);
#pragma unroll
      for (int nt = 0; nt < 4; ++nt) bfr[nt] = FR(Bl, wn * 64 + nt * 16 + li, kc * 4 + g);
#pragma unroll
      for (int mt = 0; mt < 4; ++mt)
#pragma unroll
        for (int nt = 0; nt < 4; ++nt)
          acc[mt][nt] = MFMA(af[mt], bfr[nt], acc[mt][nt]);
    }
  }

  if (which < 2) {
    unsigned short* Ob = (which == 0) ? Qb : Kb;
    unsigned short* Or = (which == 0) ? Qr : Kr;
    const float presc = (which == 0) ? PRESC : 1.f;
    __syncthreads();  // all waves done reading Al/Bl staging
    // write phase: bf16 tile [128 m][136-padded n]
#pragma unroll
    for (int mt = 0; mt < 4; ++mt)
#pragma unroll
      for (int nt = 0; nt < 4; ++nt) {
        const int nl = wn * 64 + nt * 16 + li;
#pragma unroll
        for (int r = 0; r < 4; ++r) {
          const int ml = wm * 64 + mt * 16 + 4 * g + r;
          SH[ml * 136 + nl] = f2bf((acc[mt][nt][r] + bv4[nt]) * presc);
        }
      }
    __syncthreads();
    // read phase: 8-lane groups cover one 64-col half-row -> coalesced stores
#pragma unroll
    for (int hp = 0; hp < 2; ++hp) {
#pragma unroll
      for (int pass = 0; pass < 4; ++pass) {
        const int row = pass * 32 + wave * 8 + (lane >> 3);
        const int nl = hp * 64 + (lane & 7) * 8;
        const int mg = mbase + row;
        const int bi = mg >> 11, sg = mg & (Sn - 1);
        const int ng = nbase + nl;
        const int h = ng >> 6, hd = ng & 63;
        const u16x8 v = *(const u16x8*)&SH[row * 136 + nl];
        u16x8 o;
        const float2* tp = trig + (sg << 5) + (hd >> 1);
#pragma unroll
        for (int j = 0; j < 4; ++j) {
          const float x0 = bf2f(v[2 * j]), x1 = bf2f(v[2 * j + 1]);
          const float2 cs = tp[j];
          o[2 * j] = f2bf(x0 * cs.x - x1 * cs.y);
          o[2 * j + 1] = f2bf(x1 * cs.x + x0 * cs.y);
        }
        const size_t oi = (((size_t)(bi * Hn + h)) * Sn + sg) * HDn + hd;
        *(u16x8*)(Ob + oi) = v;
        *(u16x8*)(Or + oi) = o;
      }
    }
  } else {
#pragma unroll
    for (int mt = 0; mt < 4; ++mt) {
#pragma unroll
      for (int nt = 0; nt < 4; ++nt) {
        const int n = nbase + wn * 64 + nt * 16 + li;
        const int h = n >> 6, hd = n & 63;
        const int m0 = mbase + wm * 64 + mt * 16 + 4 * g;
        const int b = m0 >> 11, s0 = m0 & (Sn - 1);
        u16x4 pk;
#pragma unroll
        for (int r = 0; r < 4; ++r) pk[r] = f2bf(acc[mt][nt][r] + bv4[nt]);
        *(u16x4*)&Vt[(((size_t)(b * Hn + h)) * HDn + hd) * Sn + s0] = pk;
      }
    }
  }
}

// ---------------------------------------------------------------------------
// 2. Output GEMM 64x128 tile (gll-staged): A bf16 [4096][1024], out f32 + bias
// ---------------------------------------------------------------------------
__global__ __launch_bounds__(256) void k_gemm_out(const unsigned short* __restrict__ A,
                                                  const unsigned short* __restrict__ Wt,
                                                  const float* __restrict__ bias,
                                                  float* __restrict__ out) {
  __shared__ unsigned short Al[64 * 64];
  __shared__ unsigned short Bl[128 * 64];
  const int tid = threadIdx.x;
  const int wave = tid >> 6, lane = tid & 63, g = lane >> 4, li = lane & 15;
  const int mbase = blockIdx.x * 64, nbase = blockIdx.y * 128;
  const int wm = wave >> 1, wn = wave & 1;

  f32x4 acc[2][4];
#pragma unroll
  for (int i = 0; i < 2; ++i)
#pragma unroll
    for (int j = 0; j < 4; ++j) acc[i][j] = Z4;

  float bv4[4];
#pragma unroll
  for (int nt = 0; nt < 4; ++nt) bv4[nt] = bias[nbase + wn * 64 + nt * 16 + li];

  const int lr8 = lane >> 3, lc = lane & 7;
  const int xc8 = (lc ^ lr8) * 8;
  const unsigned short* srcA = A + (size_t)(mbase + wave * 16 + lr8) * Dn + xc8;
  const unsigned short* srcB = Wt + (size_t)(nbase + wave * 32 + lr8) * Dn + xc8;

  for (int kb = 0; kb < Dn; kb += 64) {
    __syncthreads();
#pragma unroll
    for (int i = 0; i < 2; ++i)
      gll16(srcA + kb + (size_t)i * (8 * Dn), &Al[(wave * 16 + i * 8) * 64]);
#pragma unroll
    for (int i = 0; i < 4; ++i)
      gll16(srcB + kb + (size_t)i * (8 * Dn), &Bl[(wave * 32 + i * 8) * 64]);
    __syncthreads();
#pragma unroll
    for (int kc = 0; kc < 2; ++kc) {
      bf16x8 af[2], bfr[4];
#pragma unroll
      for (int mt = 0; mt < 2; ++mt) af[mt] = FR(Al, wm * 32 + mt * 16 + li, kc * 4 + g);
#pragma unroll
      for (int nt = 0; nt < 4; ++nt) bfr[nt] = FR(Bl, wn * 64 + nt * 16 + li, kc * 4 + g);
#pragma unroll
      for (int mt = 0; mt < 2; ++mt)
#pragma unroll
        for (int nt = 0; nt < 4; ++nt)
          acc[mt][nt] = MFMA(af[mt], bfr[nt], acc[mt][nt]);
    }
  }

#pragma unroll
  for (int mt = 0; mt < 2; ++mt)
#pragma unroll
    for (int nt = 0; nt < 4; ++nt) {
      const int n = nbase + wn * 64 + nt * 16 + li;
#pragma unroll
      for (int r = 0; r < 4; ++r) {
        const int m = mbase + wm * 32 + mt * 16 + 4 * g + r;
        out[(size_t)m * Dn + n] = acc[mt][nt][r] + bv4[nt];
      }
    }
}

// ---------------------------------------------------------------------------
// 3. Attention. grid 1024 (stride-256 map), 4 waves. Slab pass A (this round):
//    each wave computes ALL 64 block q-rows vs ITS 32-row k-slab (4 ds_reads
//    per 128-tile vs 16); per-wave partials combined via may_alias float LDS
//    reduction in Pl (before P is live; double-barrier-protected).
//    Pass B verbatim from r12 (may_alias P-store + sched_barrier fence).
// ---------------------------------------------------------------------------
__global__ __launch_bounds__(256, 4) void k_attn(
    const unsigned short* __restrict__ Qr, const unsigned short* __restrict__ Kr,
    const unsigned short* __restrict__ Qb, const unsigned short* __restrict__ Kb,
    const unsigned short* __restrict__ Vt, unsigned short* __restrict__ Zb) {
  __shared__ unsigned short KT[2][8192];  // 32 KB: passA = 128x64 Kb; passB = [Kr 64x64 | Vt 64x64]
  __shared__ unsigned short Pl[4][1024];  // 8 KB per-wave P [q][k] swizzled

  const int tid = threadIdx.x;
  const int wave = tid >> 6, lane = tid & 63, g = lane >> 4, li = lane & 15;
  // stride-256-balanced bijective map (see round-11 header)
  const int bid = blockIdx.x;
  const int x = bid & 7, m = bid >> 3;
  const int Qd = m >> 5, wv = m & 31, v = wv & 7;
  const int bh = x * 4 + (wv >> 3);
  const int qt = (Qd == 0) ? v : (Qd == 1) ? 15 - v : (Qd == 2) ? 16 + v : 31 - v;
  const int q0 = qt * 64;
  const int qw = q0 + wave * 16;
  const size_t kvbase = (size_t)bh * (Sn * HDn);

  const int lr8 = lane >> 3, lc = lane & 7;
  const int xc8 = (lc ^ lr8) * 8;  // source-side swizzle

  // pass A Q fragments: ALL 64 block q-rows (4 subtiles), prescaled Qb
  bf16x8 qbfA[4][2];
#pragma unroll
  for (int jq = 0; jq < 4; ++jq)
#pragma unroll
    for (int kc = 0; kc < 2; ++kc)
      qbfA[jq][kc] =
          *(const bf16x8*)(Qb + kvbase + (size_t)(q0 + jq * 16 + li) * HDn + kc * 32 + g * 8);

  // pass A staging: block stages one 128x64 Kb tile; wave covers rows wave*32..+31
  const unsigned short* srcPA = Kb + kvbase + (size_t)(wave * 32 + lr8) * HDn + xc8;
  // pass B staging: tw = tensor (0=Kr rows k, 1=Vt rows hd), rbB = row base
  const int tw = wave >> 1, rbB = (wave & 1) * 32;
  const unsigned short* srcKrB = Kr + kvbase + (size_t)(rbB + lr8) * HDn + xc8;
  const unsigned short* srcVtB = Vt + kvbase + (size_t)(rbB + lr8) * Sn + xc8;
  const size_t strIB = tw ? (size_t)(8 * Sn) : (size_t)(8 * HDn);
  unsigned short* myP = &Pl[wave][0];

  // diag masks: k-offset 4g+r causal-valid vs q-offset li (tile-invariant)
  bool dm[4];
#pragma unroll
  for (int r = 0; r < 4; ++r) dm[r] = (4 * g + r) <= li;

#define STAGE_PA(kb_, buf_)                                 \
  do {                                                      \
    unsigned short* d_ = &KT[buf_][(wave * 32) * 64];       \
    const unsigned short* s_ = srcPA + (size_t)(kb_)*HDn;   \
    gll16(s_, d_);                                          \
    gll16(s_ + 8 * HDn, d_ + 8 * 64);                       \
    gll16(s_ + 16 * HDn, d_ + 16 * 64);                     \
    gll16(s_ + 24 * HDn, d_ + 24 * 64);                     \
  } while (0)

#define STAGE_B(kb_, buf_)                                                    \
  do {                                                                        \
    unsigned short* d_ = &KT[buf_][tw * 4096 + rbB * 64];                     \
    const unsigned short* s_ =                                                \
        tw ? (srcVtB + (size_t)(kb_)) : (srcKrB + (size_t)(kb_)*HDn);         \
    gll16(s_, d_);                                                            \
    gll16(s_ + strIB, d_ + 8 * 64);                                           \
    gll16(s_ + 2 * strIB, d_ + 16 * 64);                                      \
    gll16(s_ + 3 * strIB, d_ + 24 * 64);                                      \
  } while (0)

  // ---- PASS A: den over ALL k; wave's own 32-row k-slab, all 64 q-rows ----
  float dacc[4][4];
#pragma unroll
  for (int jq = 0; jq < 4; ++jq)
#pragma unroll
    for (int r = 0; r < 4; ++r) dacc[jq][r] = 0.f;

  STAGE_PA(0, 0);
  __syncthreads();
  for (int t = 0; t < Sn / 128; ++t) {
    if (t + 1 < Sn / 128) STAGE_PA((t + 1) * 128, (t + 1) & 1);
    const unsigned short* TK = &KT[t & 1][0];
#pragma unroll
    for (int sub = 0; sub < 2; ++sub) {
      const int krow = wave * 32 + sub * 16 + li;  // wave's own k-slab
      const bf16x8 kf0 = FR(TK, krow, g), kf1 = FR(TK, krow, 4 + g);
      f32x4 s[4];
#pragma unroll
      for (int jq = 0; jq < 4; ++jq) {
        s[jq] = MFMA(kf0, qbfA[jq][0], Z4);
        s[jq] = MFMA(kf1, qbfA[jq][1], s[jq]);
      }
#pragma unroll
      for (int jq = 0; jq < 4; ++jq)
#pragma unroll
        for (int r = 0; r < 4; ++r) dacc[jq][r] += EXP2(s[jq][r]);
    }
    __syncthreads();
  }

  // cross-wave den reduction via Pl (1 KB; P not yet live; alias-safe)
  floata* Dred = (floata*)&Pl[0][0];  // [wave][jq][li] = 4*4*16 floats
#pragma unroll
  for (int jq = 0; jq < 4; ++jq) {
    float pd = (dacc[jq][0] + dacc[jq][1]) + (dacc[jq][2] + dacc[jq][3]);
    pd += __shfl_xor(pd, 16);
    pd += __shfl_xor(pd, 32);
    if (lane < 16) Dred[wave * 64 + jq * 16 + li] = pd;
  }
  __syncthreads();
  // lane's pass-B q = qw + li = q0 + wave*16 + li -> subtile jq == wave
  const float den = (Dred[0 * 64 + wave * 16 + li] + Dred[1 * 64 + wave * 16 + li]) +
                    (Dred[2 * 64 + wave * 16 + li] + Dred[3 * 64 + wave * 16 + li]);
  const float Lc = LOG2(den) - C2;
  const f32x4 mLc = {-Lc, -Lc, -Lc, -Lc};

  // ------------------- PASS B: w = 2^A (no max; A bounded), Z = P.V -------------
  bf16x8 qrf[2];
#pragma unroll
  for (int kc = 0; kc < 2; ++kc)
    qrf[kc] = *(const bf16x8*)(Qr + kvbase + (size_t)(qw + li) * HDn + kc * 32 + g * 8);

  f32x4 accz[4];
#pragma unroll
  for (int i = 0; i < 4; ++i) accz[i] = Z4;
  float ws[4] = {0.f, 0.f, 0.f, 0.f};
  const int NTB = qt + 1;

  STAGE_B(0, 0);
  __syncthreads();
  for (int t = 0; t < NTB; ++t) {
    if (t + 1 < NTB) STAGE_B((t + 1) * 64, (t + 1) & 1);
    const unsigned short* T0 = &KT[t & 1][0];         // Kr [k][hd]
    const unsigned short* TV = &KT[t & 1][0] + 4096;  // Vt [hd][k]
    const bool last = (t == qt);
#pragma unroll
    for (int nt = 0; nt < 4; ++nt) {
      float w4[4];
      if (!last || nt <= wave) {
        const int krow = nt * 16 + li;
        const bf16x8 kf0 = FR(T0, krow, g), kf1 = FR(T0, krow, 4 + g);
        f32x4 s = mLc;
        s = MFMA(kf0, qrf[0], s);
        s = MFMA(kf1, qrf[1], s);
        if (last && nt == wave) {  // diagonal subtile
#pragma unroll
          for (int r = 0; r < 4; ++r) {
            const float e = EXP2(EXP2(s[r]));
            w4[r] = dm[r] ? e : 0.f;
            ws[r] += w4[r];
          }
        } else {
#pragma unroll
          for (int r = 0; r < 4; ++r) {
            w4[r] = EXP2(EXP2(s[r]));
            ws[r] += w4[r];
          }
        }
      } else {
        w4[0] = w4[1] = w4[2] = w4[3] = 0.f;
      }
      const int adr = li * 64 + (((nt * 2 + (g >> 1)) ^ (li & 7)) * 8) + (g & 1) * 4;
      // may_alias store: must not be reordered against the FR() reads below
      *(uint2a*)&myP[adr] = (uint2a){cvtpk(w4[0], w4[1]), cvtpk(w4[2], w4[3])};
    }
    // hard fence: no instruction (esp. the PV ds_reads) may cross above here
    __builtin_amdgcn_sched_barrier(0);
    // PV: accz[n2] = Z[q = qw+4g+r][hd = n2*16+li]
#pragma unroll
    for (int kc = 0; kc < 2; ++kc) {
      const bf16x8 pa = FR(myP, li, kc * 4 + g);
#pragma unroll
      for (int n2 = 0; n2 < 4; ++n2) {
        const bf16x8 vb = FR(TV, n2 * 16 + li, kc * 4 + g);
        accz[n2] = MFMA(pa, vb, accz[n2]);
      }
    }
    __syncthreads();
  }

  // normalize + write bf16 [b*S+q][H*HD]
  float wsum = (ws[0] + ws[1]) + (ws[2] + ws[3]);
  wsum += __shfl_xor(wsum, 16);
  wsum += __shfl_xor(wsum, 32);  // lane holds wsum for q = qw+li
  float rw[4];
#pragma unroll
  for (int r = 0; r < 4; ++r) rw[r] = 1.f / __shfl(wsum, 4 * g + r);
  const int b = bh >> 4, h = bh & 15;
#pragma unroll
  for (int n2 = 0; n2 < 4; ++n2) {
#pragma unroll
    for (int r = 0; r < 4; ++r) {
      const int hd = n2 * 16 + li;
      const int q = qw + 4 * g + r;
      Zb[((size_t)(b * Sn + q)) * Dn + h * HDn + hd] = f2bf(accz[n2][r] * rw[r]);
    }
  }
#undef STAGE_PA
#undef STAGE_B
}

// ---------------------------------------------------------------------------
extern "C" void kernel_launch(void* const* d_in, const int* in_sizes, int n_in,
                              void* d_out, int out_size, void* d_ws, size_t ws_size,
                              hipStream_t stream) {
  const float* query = (const float*)d_in[0];
  const float* key   = (const float*)d_in[1];
  const float* value = (const float*)d_in[2];
  const float* Wq = (const float*)d_in[4];
  const float* bq = (const float*)d_in[5];
  const float* Wk = (const float*)d_in[6];
  const float* bk = (const float*)d_in[7];
  const float* Wv = (const float*)d_in[8];
  const float* bv = (const float*)d_in[9];
  const float* Wo = (const float*)d_in[10];
  const float* bo = (const float*)d_in[11];

  char* ws = (char*)d_ws;
  const size_t MB = 1ull << 20;
  unsigned short* Wqt = (unsigned short*)(ws + 0 * MB);
  unsigned short* Wkt = (unsigned short*)(ws + 2 * MB);
  unsigned short* Wvt = (unsigned short*)(ws + 4 * MB);
  unsigned short* Wot = (unsigned short*)(ws + 6 * MB);
  float2* trig        = (float2*)(ws + 8 * MB);           // 512 KB
  unsigned short* Qa  = (unsigned short*)(ws + 9 * MB);   // bf16 activations
  unsigned short* Ka  = (unsigned short*)(ws + 17 * MB);
  unsigned short* Va  = (unsigned short*)(ws + 25 * MB);
  unsigned short* Qb  = (unsigned short*)(ws + 33 * MB);  // [b,h,s,hd] (Q prescaled)
  unsigned short* Kb  = (unsigned short*)(ws + 41 * MB);
  unsigned short* Qr  = (unsigned short*)(ws + 49 * MB);
  unsigned short* Kr  = (unsigned short*)(ws + 57 * MB);
  unsigned short* Vt  = (unsigned short*)(ws + 65 * MB);  // [b,h,hd,s]
  unsigned short* Zb  = (unsigned short*)(ws + 73 * MB);  // [m][1024] bf16

  k_pre<<<7424, 256, 0, stream>>>(Wq, Wk, Wv, Wo, Wqt, Wkt, Wvt, Wot,
                                  query, key, value, Qa, Ka, Va, trig);
  k_gemm_proj<<<dim3(32, 8, 3), 256, 0, stream>>>(Qa, Ka, Va, Wqt, Wkt, Wvt,
                                                  bq, bk, bv, trig, Qb, Kb, Qr, Kr, Vt);
  k_attn<<<1024, 256, 0, stream>>>(Qr, Kr, Qb, Kb, Vt, Zb);
  k_gemm_out<<<dim3(64, 8), 256, 0, stream>>>(Zb, Wot, bo, (float*)d_out);
}